// Round 11
// baseline (1199.678 us; speedup 1.0000x reference)
//
#include <hip/hip_runtime.h>

typedef unsigned short u16;
typedef unsigned int u32;
typedef __attribute__((ext_vector_type(8))) _Float16 half8;
typedef __attribute__((ext_vector_type(2))) __fp16 fp16x2;
typedef __attribute__((ext_vector_type(4))) float floatx4;

#define E_TOTAL 65536

__device__ __forceinline__ u32 pk16(float x0, float x1) {
    union { fp16x2 h; u32 u; } c;
    c.h = __builtin_amdgcn_cvt_pkrtz(x0, x1);
    return c.u;
}
union Frag8h { u32 u[4]; half8 v; };

// ws layout (floats): [0:768] per-graph stat sums, [768:1024] unused (was mu),
// [1024:1056] unused; ints [1056:1088] = binv. If ws_size >= 991232 B:
// floats [2048:6144] = ablation scratch (diagnostic, never read).

// ---------------- Init: zero stats + probe MFMA k-pairing (fused) ----------------
__global__ __launch_bounds__(1024) void k_init(float* __restrict__ ws, int* __restrict__ binv) {
    const int tid = threadIdx.x;
    for (int i = tid; i < 1056; i += 1024) ws[i] = 0.0f;
    if (tid < 64) {
        const int lane = tid;
        const int q = lane >> 4;
        if (lane < 32) binv[lane] = lane;    // default identity (safety)
        half8 bfr;
        #pragma unroll
        for (int j = 0; j < 8; ++j) bfr[j] = (_Float16)(float)(q*8 + j + 1);
        #pragma unroll
        for (int s = 0; s < 32; ++s) {
            const int qa = s >> 3, ja = s & 7;
            half8 afr;
            #pragma unroll
            for (int j = 0; j < 8; ++j) afr[j] = (_Float16)0.0f;
            if (q == qa) afr[ja] = (_Float16)1.0f;
            floatx4 dc = {0.0f, 0.0f, 0.0f, 0.0f};
            dc = __builtin_amdgcn_mfma_f32_16x16x32_f16(afr, bfr, dc, 0, 0, 0);
            if (lane == 0) {
                const int sB = (int)(dc[0] + 0.5f) - 1;
                if (sB >= 0 && sB < 32) binv[sB] = s;
            }
        }
    }
}

// ---------------- Kernel 1: heavy per-edge conv (R8-diet, 367us verified) ----------
__global__ __launch_bounds__(256) void k_edge_heavy(
    const float* __restrict__ node_fea, const float* __restrict__ edge_attr,
    const int* __restrict__ edge_index, const int* __restrict__ xsp,
    const float* __restrict__ w_rh, const float* __restrict__ b_rh,
    const float* __restrict__ w_ro, const float* __restrict__ b_ro,
    const float* __restrict__ w_pre, const float* __restrict__ b_pre,
    const float* __restrict__ w_sc, const float* __restrict__ w_post_s,
    const float* __restrict__ b_post_s, const float* __restrict__ w_post_v,
    const int* __restrict__ binv,
    float* __restrict__ out)
{
    __shared__ __align__(16) u16 a_rbf[16 * 128];
    __shared__ __align__(16) u16 a_h[16 * 64];
    __shared__ __align__(16) float sh_wt[16][258];
    __shared__ float sh_sin[16][80];
    __shared__ float sh_vl[16][3][32];
    __shared__ float sh_acc[16][56];
    __shared__ float sh_es0[16][16];
    __shared__ float sh_y1[16][4];
    __shared__ int   sh_kmap[32];

    const int tid = threadIdx.x;
    const int ed = tid >> 4, l16 = tid & 15;
    const int lane = tid & 63, w = tid >> 6;
    const int quad = lane >> 4, l15 = lane & 15;
    const int e = blockIdx.x * 16 + ed;

    if (tid < 32) sh_kmap[tid] = binv[tid];

    const int ni = edge_index[e];
    const int nj = edge_index[E_TOTAL + e];
    const float4 ea = *(const float4*)(edge_attr + 4*e);
    const float d  = ea.x;
    const float vx = ea.y, vy = ea.z, vz = ea.w;
    const float invn = 1.0f / (sqrtf(vx*vx + vy*vy + vz*vz) + 1e-12f);
    const float Y0 = 1.7320508075688772f * vx * invn;
    const float Y1 = 1.7320508075688772f * vy * invn;
    const float Y2 = 1.7320508075688772f * vz * invn;
    if (l16 == 0) { sh_y1[ed][0] = Y0; sh_y1[ed][1] = Y1; sh_y1[ed][2] = Y2; }

    const float C128 = -0.5f * (127.0f/6.0f) * (127.0f/6.0f);
    const float S128 = 6.0f/127.0f;
    {
        Frag8h thi;
        #pragma unroll
        for (int r2 = 0; r2 < 4; ++r2) {
            const int b0i = l16*8 + 2*r2;
            const float t0 = d - S128 * (float)b0i;
            const float t1 = d - S128 * (float)(b0i + 1);
            const float x0 = expf(C128 * t0 * t0);
            const float x1 = expf(C128 * t1 * t1);
            thi.u[r2] = pk16(x0, x1);
        }
        *(half8*)&a_rbf[(l16*16 + ed)*8] = thi.v;
    }
    {
        const float t = d - 0.4f * (float)l16;
        sh_es0[ed][l16] = expf(-3.125f * t * t);
    }

    const float rs80 = 0.11180339887498949f;
    const float rs32 = 0.17677669529663689f;
    {
        const float* fi = node_fea + (size_t)ni * 80;
        const float* fj = node_fea + (size_t)nj * 80;
        sh_sin[ed][2*l16+0]    = fi[2*l16+0] * rs80;
        sh_sin[ed][2*l16+1]    = fi[2*l16+1] * rs80;
        sh_sin[ed][32+2*l16+0] = fj[2*l16+0] * rs80;
        sh_sin[ed][32+2*l16+1] = fj[2*l16+1] * rs80;
        #pragma unroll
        for (int c = 0; c < 3; ++c) {
            sh_vl[ed][c][l16]      = fi[32 + 3*l16 + c] * rs32;
            sh_vl[ed][c][16 + l16] = fj[32 + 3*l16 + c] * rs32;
        }
    }
    for (int s = tid; s < 16*56; s += 256) (&sh_acc[0][0])[s] = 0.0f;
    __syncthreads();

    int km[8];
    u32 voff0[8], voff1[8];
    #pragma unroll
    for (int j = 0; j < 8; ++j) {
        km[j] = sh_kmap[quad*8 + j];
        voff0[j] = (u32)(km[j] * 3840 + l15);
        voff1[j] = voff0[j] + 32u * 3840u;
    }

    float my_sc;
    {
        const int o = l16;
        float es = b_pre[o];
        float sc = 0.0f;
        const int p = 4*xsp[ni] + xsp[nj];
        #pragma unroll
        for (int i = 0; i < 16; ++i) {
            const float g = sh_es0[ed][i];
            es += g * w_pre[i*16 + o];
            sc += g * w_sc[(i*16 + p)*16 + o];
        }
        sh_sin[ed][64 + o] = es * rs80;
        my_sc = sc * 0.0625f;
    }

    {
        floatx4 hacc = {0.0f, 0.0f, 0.0f, 0.0f};
        #pragma unroll
        for (int kk = 0; kk < 4; ++kk) {
            const half8 ah = *(const half8*)&a_rbf[((kk*4 + quad)*16 + l15)*8];
            Frag8h bh;
            #pragma unroll
            for (int jj = 0; jj < 4; ++jj) {
                const float x0 = w_rh[(size_t)(kk*32 + km[2*jj+0])*64 + w*16 + l15];
                const float x1 = w_rh[(size_t)(kk*32 + km[2*jj+1])*64 + w*16 + l15];
                bh.u[jj] = pk16(x0, x1);
            }
            hacc = __builtin_amdgcn_mfma_f32_16x16x32_f16(ah, bh.v, hacc, 0, 0, 0);
        }
        const int hn = w*16 + l15;
        const float bb = b_rh[hn];
        const int k8 = hn >> 3, j2 = hn & 7;
        #pragma unroll
        for (int r = 0; r < 4; ++r) {
            const float x = hacc[r] + bb;
            const float s = x / (1.0f + expf(-x));
            const int m = quad*4 + r;
            union { _Float16 h; u16 u; } cv; cv.h = (_Float16)s;
            a_h[(k8*16 + m)*8 + j2] = cv.u;
        }
    }
    __syncthreads();

    const half8 a0 = *(const half8*)&a_h[((0*4 + quad)*16 + l15)*8];
    const half8 a1 = *(const half8*)&a_h[((1*4 + quad)*16 + l15)*8];

    for (int ch = 0; ch < 15; ++ch) {
        const int coff = ch * 256;
        floatx4 acc[4];
        float bias[4];
        #pragma unroll
        for (int ct = 0; ct < 4; ++ct) {
            const int sgct = __builtin_amdgcn_readfirstlane(ch*16 + w*4 + ct);
            const float* bp = w_ro + sgct*16;
            float f0[8], f1[8];
            #pragma unroll
            for (int j = 0; j < 8; ++j) {
                f0[j] = bp[voff0[j]];
                f1[j] = bp[voff1[j]];
            }
            Frag8h b0, b1;
            #pragma unroll
            for (int jj = 0; jj < 4; ++jj) {
                b0.u[jj] = pk16(f0[2*jj], f0[2*jj+1]);
                b1.u[jj] = pk16(f1[2*jj], f1[2*jj+1]);
            }
            floatx4 a = {0.0f, 0.0f, 0.0f, 0.0f};
            a = __builtin_amdgcn_mfma_f32_16x16x32_f16(a0, b0.v, a, 0, 0, 0);
            a = __builtin_amdgcn_mfma_f32_16x16x32_f16(a1, b1.v, a, 0, 0, 0);
            acc[ct] = a;
            bias[ct] = b_ro[sgct*16 + l15];
        }
        __syncthreads();
        #pragma unroll
        for (int ct = 0; ct < 4; ++ct) {
            const int col = w*64 + ct*16 + l15;
            #pragma unroll
            for (int r = 0; r < 4; ++r)
                sh_wt[quad*4 + r][col] = acc[ct][r] + bias[ct];
        }
        __syncthreads();

        if (ch <= 7) {
            const int hi = (ch == 7) ? 1920 : (coff + 256);
            for (int idx = tid; idx < 384; idx += 256) {
                const int eo = idx / 24, o = idx % 24;
                const int i0 = (coff > o) ? (coff - o + 23) / 24 : 0;
                int i1 = (hi - o + 23) / 24; if (i1 > 80) i1 = 80;
                float a = 0.0f;
                for (int i = i0; i < i1; ++i)
                    a += sh_sin[eo][i] * sh_wt[eo][i*24 + o - coff];
                sh_acc[eo][o] += a;
            }
        }
        if (ch == 7) {
            for (int idx = tid; idx < 128; idx += 256) {
                const int eo = idx >> 3, o = idx & 7;
                float a = 0.0f;
                #pragma unroll
                for (int i = 0; i < 16; ++i)
                    a += sh_sin[eo][i] * sh_wt[eo][128 + i*8 + o];
                sh_acc[eo][24 + o] += a;
            }
        }
        if (ch == 8 || ch == 9) {
            const int ib = (ch == 8) ? 16 : 48;
            for (int idx = tid; idx < 128; idx += 256) {
                const int eo = idx >> 3, o = idx & 7;
                float a = 0.0f;
                #pragma unroll
                for (int i2 = 0; i2 < 32; ++i2)
                    a += sh_sin[eo][ib + i2] * sh_wt[eo][i2*8 + o];
                sh_acc[eo][24 + o] += a;
            }
        }
        if (ch == 10) {
            for (int idx = tid; idx < 384; idx += 256) {
                const int eo = idx / 24, rem = idx % 24;
                const int o = rem / 3, cc = rem % 3;
                float a = 0.0f;
                #pragma unroll
                for (int i = 0; i < 32; ++i)
                    a += sh_vl[eo][cc][i] * sh_wt[eo][i*8 + o];
                sh_acc[eo][32 + o*3 + cc] += a;
            }
        }
        if (ch >= 11 && ch <= 13) {
            const int rel = coff - 2816;
            for (int idx = tid; idx < 384; idx += 256) {
                const int eo = idx / 24, o = idx % 24;
                const int i0 = (rel > o) ? (rel - o + 23) / 24 : 0;
                int i1 = (rel + 256 - o + 23) / 24; if (i1 > 32) i1 = 32;
                const float Ya = sh_y1[eo][0], Yb = sh_y1[eo][1], Yc = sh_y1[eo][2];
                float a = 0.0f;
                for (int i = i0; i < i1; ++i) {
                    const float qv = sh_vl[eo][0][i]*Ya + sh_vl[eo][1][i]*Yb
                                   + sh_vl[eo][2][i]*Yc;
                    a += qv * sh_wt[eo][i*24 + o - rel];
                }
                sh_acc[eo][o] += a * 0.57735026918962573f;
            }
        }
        if (ch == 14) {
            for (int idx = tid; idx < 384; idx += 256) {
                const int eo = idx / 24, rem = idx % 24;
                const int o = rem / 3, cc = rem % 3;
                const int c1 = (cc < 2) ? cc + 1 : 0;
                const int c2 = (c1 < 2) ? c1 + 1 : 0;
                const float Yp = sh_y1[eo][c2];
                const float Ym = sh_y1[eo][c1];
                float a = 0.0f;
                #pragma unroll
                for (int i = 0; i < 32; ++i)
                    a += (sh_vl[eo][c1][i]*Yp - sh_vl[eo][c2][i]*Ym) * sh_wt[eo][i*8 + o];
                sh_acc[eo][32 + o*3 + cc] += a * 0.70710678118654746f;
            }
        }
    }
    __syncthreads();

    {
        const int o = l16;
        float a = b_post_s[o] + my_sc;
        #pragma unroll
        for (int i = 0; i < 16; ++i) {
            const float sv = sh_acc[ed][i];
            a += (sv / (1.0f + expf(-sv))) * w_post_s[i*16 + o];
        }
        out[(size_t)e*40 + o] = a;
    }
    if (l16 < 8) {
        const int o = l16;
        const float Ya = sh_y1[ed][0], Yb = sh_y1[ed][1], Yc = sh_y1[ed][2];
        float r0 = 0.0f, r1 = 0.0f, r2 = 0.0f;
        #pragma unroll
        for (int i = 0; i < 8; ++i) {
            const float g  = 1.0f / (1.0f + expf(-sh_acc[ed][16 + i]));
            const float a2 = sh_acc[ed][24 + i];
            const float ww = w_post_v[i*8 + o];
            r0 += (a2*Ya + sh_acc[ed][32 + i*3 + 0]) * g * ww;
            r1 += (a2*Yb + sh_acc[ed][32 + i*3 + 1]) * g * ww;
            r2 += (a2*Yc + sh_acc[ed][32 + i*3 + 2]) * g * ww;
        }
        out[(size_t)e*40 + 16 + o*3 + 0] = r0;
        out[(size_t)e*40 + 16 + o*3 + 1] = r1;
        out[(size_t)e*40 + 16 + o*3 + 2] = r2;
    }
}

// ---------------- ABLATION A: loads+convert+MFMA+barriers, NO consumers -------------
// Writes keep-alive values to ws scratch (never read). Grid 8192 (2x) for visibility.
__global__ __launch_bounds__(256) void k_abl_lm(
    const float* __restrict__ node_fea, const float* __restrict__ edge_attr,
    const int* __restrict__ edge_index,
    const float* __restrict__ w_rh, const float* __restrict__ b_rh,
    const float* __restrict__ w_ro, const float* __restrict__ b_ro,
    const int* __restrict__ binv, float* scr)
{
    __shared__ __align__(16) u16 a_rbf[16 * 128];
    __shared__ __align__(16) u16 a_h[16 * 64];
    __shared__ __align__(16) float sh_wt[16][258];
    __shared__ float sh_sin[16][80];
    __shared__ float sh_vl[16][3][32];
    __shared__ float sh_acc[16][56];
    __shared__ float sh_es0[16][16];
    __shared__ float sh_y1[16][4];
    __shared__ int   sh_kmap[32];

    const int tid = threadIdx.x;
    const int ed = tid >> 4, l16 = tid & 15;
    const int lane = tid & 63, w = tid >> 6;
    const int quad = lane >> 4, l15 = lane & 15;
    const int e = (blockIdx.x & 4095) * 16 + ed;

    if (tid < 32) sh_kmap[tid] = binv[tid];

    const int ni = edge_index[e];
    const int nj = edge_index[E_TOTAL + e];
    const float4 ea = *(const float4*)(edge_attr + 4*e);
    const float d  = ea.x;
    const float vx = ea.y, vy = ea.z, vz = ea.w;
    const float invn = 1.0f / (sqrtf(vx*vx + vy*vy + vz*vz) + 1e-12f);
    if (l16 == 0) {
        sh_y1[ed][0] = 1.7320508075688772f * vx * invn;
        sh_y1[ed][1] = 1.7320508075688772f * vy * invn;
        sh_y1[ed][2] = 1.7320508075688772f * vz * invn;
    }
    const float C128 = -0.5f * (127.0f/6.0f) * (127.0f/6.0f);
    const float S128 = 6.0f/127.0f;
    {
        Frag8h thi;
        #pragma unroll
        for (int r2 = 0; r2 < 4; ++r2) {
            const int b0i = l16*8 + 2*r2;
            const float t0 = d - S128 * (float)b0i;
            const float t1 = d - S128 * (float)(b0i + 1);
            thi.u[r2] = pk16(expf(C128*t0*t0), expf(C128*t1*t1));
        }
        *(half8*)&a_rbf[(l16*16 + ed)*8] = thi.v;
    }
    {
        const float t = d - 0.4f * (float)l16;
        sh_es0[ed][l16] = expf(-3.125f * t * t);
    }
    const float rs80 = 0.11180339887498949f;
    const float rs32 = 0.17677669529663689f;
    {
        const float* fi = node_fea + (size_t)ni * 80;
        const float* fj = node_fea + (size_t)nj * 80;
        sh_sin[ed][2*l16+0]    = fi[2*l16+0] * rs80;
        sh_sin[ed][2*l16+1]    = fi[2*l16+1] * rs80;
        sh_sin[ed][32+2*l16+0] = fj[2*l16+0] * rs80;
        sh_sin[ed][32+2*l16+1] = fj[2*l16+1] * rs80;
        #pragma unroll
        for (int c = 0; c < 3; ++c) {
            sh_vl[ed][c][l16]      = fi[32 + 3*l16 + c] * rs32;
            sh_vl[ed][c][16 + l16] = fj[32 + 3*l16 + c] * rs32;
        }
    }
    for (int s = tid; s < 16*56; s += 256) (&sh_acc[0][0])[s] = 0.0f;
    __syncthreads();

    int km[8];
    u32 voff0[8], voff1[8];
    #pragma unroll
    for (int j = 0; j < 8; ++j) {
        km[j] = sh_kmap[quad*8 + j];
        voff0[j] = (u32)(km[j] * 3840 + l15);
        voff1[j] = voff0[j] + 32u * 3840u;
    }

    // h-GEMM (kept: part of load/MFMA phase)
    {
        floatx4 hacc = {0.0f, 0.0f, 0.0f, 0.0f};
        #pragma unroll
        for (int kk = 0; kk < 4; ++kk) {
            const half8 ah = *(const half8*)&a_rbf[((kk*4 + quad)*16 + l15)*8];
            Frag8h bh;
            #pragma unroll
            for (int jj = 0; jj < 4; ++jj) {
                const float x0 = w_rh[(size_t)(kk*32 + km[2*jj+0])*64 + w*16 + l15];
                const float x1 = w_rh[(size_t)(kk*32 + km[2*jj+1])*64 + w*16 + l15];
                bh.u[jj] = pk16(x0, x1);
            }
            hacc = __builtin_amdgcn_mfma_f32_16x16x32_f16(ah, bh.v, hacc, 0, 0, 0);
        }
        const int hn = w*16 + l15;
        const float bb = b_rh[hn];
        const int k8 = hn >> 3, j2 = hn & 7;
        #pragma unroll
        for (int r = 0; r < 4; ++r) {
            const float x = hacc[r] + bb;
            const float s = x / (1.0f + expf(-x));
            union { _Float16 h; u16 u; } cv; cv.h = (_Float16)s;
            a_h[(k8*16 + (quad*4+r))*8 + j2] = cv.u;
        }
    }
    __syncthreads();

    const half8 a0 = *(const half8*)&a_h[((0*4 + quad)*16 + l15)*8];
    const half8 a1 = *(const half8*)&a_h[((1*4 + quad)*16 + l15)*8];

    float keep = 0.0f;
    for (int ch = 0; ch < 15; ++ch) {
        floatx4 acc[4];
        float bias[4];
        #pragma unroll
        for (int ct = 0; ct < 4; ++ct) {
            const int sgct = __builtin_amdgcn_readfirstlane(ch*16 + w*4 + ct);
            const float* bp = w_ro + sgct*16;
            float f0[8], f1[8];
            #pragma unroll
            for (int j = 0; j < 8; ++j) {
                f0[j] = bp[voff0[j]];
                f1[j] = bp[voff1[j]];
            }
            Frag8h b0, b1;
            #pragma unroll
            for (int jj = 0; jj < 4; ++jj) {
                b0.u[jj] = pk16(f0[2*jj], f0[2*jj+1]);
                b1.u[jj] = pk16(f1[2*jj], f1[2*jj+1]);
            }
            floatx4 a = {0.0f, 0.0f, 0.0f, 0.0f};
            a = __builtin_amdgcn_mfma_f32_16x16x32_f16(a0, b0.v, a, 0, 0, 0);
            a = __builtin_amdgcn_mfma_f32_16x16x32_f16(a1, b1.v, a, 0, 0, 0);
            acc[ct] = a;
            bias[ct] = b_ro[sgct*16 + l15];
        }
        __syncthreads();
        #pragma unroll
        for (int ct = 0; ct < 4; ++ct) {
            const int col = w*64 + ct*16 + l15;
            #pragma unroll
            for (int r = 0; r < 4; ++r)
                sh_wt[quad*4 + r][col] = acc[ct][r] + bias[ct];
            keep += acc[ct][0];
        }
        __syncthreads();
        // consumers DELETED (ablation)
    }
    __syncthreads();
    // keep sh_wt stores + acc live; scratch is write-only garbage
    keep += sh_wt[ed][l16] + sh_vl[ed][0][l16] + sh_sin[ed][l16] + sh_es0[ed][l16&15]
          + sh_y1[ed][0] + sh_acc[ed][l16];
    scr[(blockIdx.x * 256u + tid) & 4095u] = keep;
}

// ---------------- ABLATION B: barriers+sh_wt writes+consumers, NO loads/MFMA --------
__global__ __launch_bounds__(256) void k_abl_cons(
    const float* __restrict__ node_fea, const float* __restrict__ edge_attr,
    const int* __restrict__ edge_index, float* scr)
{
    __shared__ __align__(16) float sh_wt[16][258];
    __shared__ float sh_sin[16][80];
    __shared__ float sh_vl[16][3][32];
    __shared__ float sh_acc[16][56];
    __shared__ float sh_y1[16][4];

    const int tid = threadIdx.x;
    const int ed = tid >> 4, l16 = tid & 15;
    const int lane = tid & 63, w = tid >> 6;
    const int quad = lane >> 4, l15 = lane & 15;
    const int e = (blockIdx.x & 4095) * 16 + ed;

    const int ni = edge_index[e];
    const int nj = edge_index[E_TOTAL + e];
    const float4 ea = *(const float4*)(edge_attr + 4*e);
    const float vx = ea.y, vy = ea.z, vz = ea.w;
    const float invn = 1.0f / (sqrtf(vx*vx + vy*vy + vz*vz) + 1e-12f);
    if (l16 == 0) {
        sh_y1[ed][0] = 1.7320508075688772f * vx * invn;
        sh_y1[ed][1] = 1.7320508075688772f * vy * invn;
        sh_y1[ed][2] = 1.7320508075688772f * vz * invn;
    }
    const float rs80 = 0.11180339887498949f;
    const float rs32 = 0.17677669529663689f;
    {
        const float* fi = node_fea + (size_t)ni * 80;
        const float* fj = node_fea + (size_t)nj * 80;
        sh_sin[ed][2*l16+0]    = fi[2*l16+0] * rs80;
        sh_sin[ed][2*l16+1]    = fi[2*l16+1] * rs80;
        sh_sin[ed][32+2*l16+0] = fj[2*l16+0] * rs80;
        sh_sin[ed][32+2*l16+1] = fj[2*l16+1] * rs80;
        sh_sin[ed][64+l16]     = fi[l16] * rs80;      // stand-in (edge_s skipped)
        #pragma unroll
        for (int c = 0; c < 3; ++c) {
            sh_vl[ed][c][l16]      = fi[32 + 3*l16 + c] * rs32;
            sh_vl[ed][c][16 + l16] = fj[32 + 3*l16 + c] * rs32;
        }
    }
    for (int s = tid; s < 16*56; s += 256) (&sh_acc[0][0])[s] = 0.0f;
    __syncthreads();

    for (int ch = 0; ch < 15; ++ch) {
        const int coff = ch * 256;
        // constant acc (loads/MFMA DELETED)
        floatx4 acc[4];
        float bias[4];
        #pragma unroll
        for (int ct = 0; ct < 4; ++ct) {
            #pragma unroll
            for (int r = 0; r < 4; ++r) acc[ct][r] = (float)(((tid + ct*3 + r) & 15)) * 0.0625f;
            bias[ct] = 0.0f;
        }
        __syncthreads();
        #pragma unroll
        for (int ct = 0; ct < 4; ++ct) {
            const int col = w*64 + ct*16 + l15;
            #pragma unroll
            for (int r = 0; r < 4; ++r)
                sh_wt[quad*4 + r][col] = acc[ct][r] + bias[ct];
        }
        __syncthreads();

        if (ch <= 7) {
            const int hi = (ch == 7) ? 1920 : (coff + 256);
            for (int idx = tid; idx < 384; idx += 256) {
                const int eo = idx / 24, o = idx % 24;
                const int i0 = (coff > o) ? (coff - o + 23) / 24 : 0;
                int i1 = (hi - o + 23) / 24; if (i1 > 80) i1 = 80;
                float a = 0.0f;
                for (int i = i0; i < i1; ++i)
                    a += sh_sin[eo][i] * sh_wt[eo][i*24 + o - coff];
                sh_acc[eo][o] += a;
            }
        }
        if (ch == 7) {
            for (int idx = tid; idx < 128; idx += 256) {
                const int eo = idx >> 3, o = idx & 7;
                float a = 0.0f;
                #pragma unroll
                for (int i = 0; i < 16; ++i)
                    a += sh_sin[eo][i] * sh_wt[eo][128 + i*8 + o];
                sh_acc[eo][24 + o] += a;
            }
        }
        if (ch == 8 || ch == 9) {
            const int ib = (ch == 8) ? 16 : 48;
            for (int idx = tid; idx < 128; idx += 256) {
                const int eo = idx >> 3, o = idx & 7;
                float a = 0.0f;
                #pragma unroll
                for (int i2 = 0; i2 < 32; ++i2)
                    a += sh_sin[eo][ib + i2] * sh_wt[eo][i2*8 + o];
                sh_acc[eo][24 + o] += a;
            }
        }
        if (ch == 10) {
            for (int idx = tid; idx < 384; idx += 256) {
                const int eo = idx / 24, rem = idx % 24;
                const int o = rem / 3, cc = rem % 3;
                float a = 0.0f;
                #pragma unroll
                for (int i = 0; i < 32; ++i)
                    a += sh_vl[eo][cc][i] * sh_wt[eo][i*8 + o];
                sh_acc[eo][32 + o*3 + cc] += a;
            }
        }
        if (ch >= 11 && ch <= 13) {
            const int rel = coff - 2816;
            for (int idx = tid; idx < 384; idx += 256) {
                const int eo = idx / 24, o = idx % 24;
                const int i0 = (rel > o) ? (rel - o + 23) / 24 : 0;
                int i1 = (rel + 256 - o + 23) / 24; if (i1 > 32) i1 = 32;
                const float Ya = sh_y1[eo][0], Yb = sh_y1[eo][1], Yc = sh_y1[eo][2];
                float a = 0.0f;
                for (int i = i0; i < i1; ++i) {
                    const float qv = sh_vl[eo][0][i]*Ya + sh_vl[eo][1][i]*Yb
                                   + sh_vl[eo][2][i]*Yc;
                    a += qv * sh_wt[eo][i*24 + o - rel];
                }
                sh_acc[eo][o] += a * 0.57735026918962573f;
            }
        }
        if (ch == 14) {
            for (int idx = tid; idx < 384; idx += 256) {
                const int eo = idx / 24, rem = idx % 24;
                const int o = rem / 3, cc = rem % 3;
                const int c1 = (cc < 2) ? cc + 1 : 0;
                const int c2 = (c1 < 2) ? c1 + 1 : 0;
                const float Yp = sh_y1[eo][c2];
                const float Ym = sh_y1[eo][c1];
                float a = 0.0f;
                #pragma unroll
                for (int i = 0; i < 32; ++i)
                    a += (sh_vl[eo][c1][i]*Yp - sh_vl[eo][c2][i]*Ym) * sh_wt[eo][i*8 + o];
                sh_acc[eo][32 + o*3 + cc] += a * 0.70710678118654746f;
            }
        }
    }
    __syncthreads();
    scr[(blockIdx.x * 256u + tid) & 4095u] =
        sh_acc[ed][l16] + sh_acc[ed][24 + (l16 & 7)] + sh_acc[ed][32 + l16];
}

// ---------------- Kernel 2a: per-edge LDS-atomic segment stats ----------------------
__global__ __launch_bounds__(256) void k_stats_partial(
    const float* __restrict__ sv, const int* __restrict__ edge_index,
    const int* __restrict__ batch, float* __restrict__ ws)
{
    __shared__ float bins[768];
    const int tid = threadIdx.x;
    for (int s = tid; s < 768; s += 256) bins[s] = 0.0f;
    __syncthreads();

    const int e = blockIdx.x * 256 + tid;
    const int g = batch[edge_index[e]];
    const float* p = sv + (size_t)e * 40;
    float v[40];
    #pragma unroll
    for (int j = 0; j < 40; ++j) v[j] = p[j];

    float* bg = bins + g * 48;
    #pragma unroll
    for (int chn = 0; chn < 16; ++chn) {
        atomicAdd(&bg[chn],      v[chn]);
        atomicAdd(&bg[16 + chn], v[chn] * v[chn]);
    }
    #pragma unroll
    for (int o = 0; o < 8; ++o) {
        const float a = v[16 + o*3], b = v[16 + o*3 + 1], c = v[16 + o*3 + 2];
        atomicAdd(&bg[32 + o], a*a + b*b + c*c);
    }
    atomicAdd(&bg[40], 1.0f);
    __syncthreads();

    for (int s = tid; s < 768; s += 256) {
        const float x = bins[s];
        if (x != 0.0f) atomicAdd(&ws[s], x);
    }
}

// ---------------- Kernel 4: stats-finalize (folded) + LN + skip + edge projections --
__global__ __launch_bounds__(256) void k_edge_final(
    float* buf, const float* __restrict__ ws,
    const float* __restrict__ edge_attr, const int* __restrict__ edge_index,
    const int* __restrict__ batch,
    const float* __restrict__ ln_w_s, const float* __restrict__ ln_b_s,
    const float* __restrict__ ln_w_v, const float* __restrict__ w_skip,
    const float* __restrict__ w_edge_s, const float* __restrict__ b_edge_s,
    const float* __restrict__ w_edge_v)
{
    __shared__ float sh_mu[16][16];
    __shared__ float sh_is[16], sh_iv[16];
    __shared__ float sh_lws[16], sh_lbs[16], sh_lwv[8];
    __shared__ float sh_skip[16][16], sh_wes[16][16], sh_bes[16], sh_wev[8][8];
    const int tid = threadIdx.x;
    // folded stats_final: each block recomputes 16 graphs' mu / inv_rms from sums
    if (tid < 16) {
        const int g = tid;
        float cnt = ws[g*48 + 40]; if (cnt < 1.0f) cnt = 1.0f;
        const float ic = 1.0f / cnt;
        float vs = 0.0f;
        for (int chn = 0; chn < 16; ++chn) {
            const float mu = ws[g*48 + chn] * ic;
            sh_mu[g][chn] = mu;
            vs += ws[g*48 + 16 + chn] * ic - mu * mu;
        }
        if (vs < 0.0f) vs = 0.0f;
        sh_is[g] = 1.0f / sqrtf(vs * (1.0f/16.0f) + 1e-5f);
        float vv = 0.0f;
        for (int o = 0; o < 8; ++o) vv += ws[g*48 + 32 + o];
        vv = vv * ic * (1.0f/3.0f) * (1.0f/8.0f);
        sh_iv[g] = 1.0f / sqrtf(vv + 1e-5f);
    }
    sh_skip[tid >> 4][tid & 15] = w_skip[tid];
    sh_wes[tid >> 4][tid & 15]  = w_edge_s[tid];
    if (tid < 16) {
        sh_lws[tid] = ln_w_s[tid];
        sh_lbs[tid] = ln_b_s[tid];
        sh_bes[tid] = b_edge_s[tid];
    }
    if (tid < 8)  sh_lwv[tid] = ln_w_v[tid];
    if (tid < 64) sh_wev[tid >> 3][tid & 7] = w_edge_v[tid];
    __syncthreads();

    const int e = blockIdx.x * 256 + tid;
    const int g = batch[edge_index[e]];
    const float d = edge_attr[4*e];
    float es0[16];
    #pragma unroll
    for (int b = 0; b < 16; ++b) {
        const float t = d - 0.4f * (float)b;
        es0[b] = expf(-3.125f * t * t);
    }
    float p[40];
    float* pb = buf + (size_t)e * 40;
    #pragma unroll
    for (int j = 0; j < 40; ++j) p[j] = pb[j];

    const float is = sh_is[g];
    float sn[16];
    #pragma unroll
    for (int chn = 0; chn < 16; ++chn)
        sn[chn] = (p[chn] - sh_mu[g][chn]) * is * sh_lws[chn] + sh_lbs[chn];
    #pragma unroll
    for (int b = 0; b < 16; ++b) {
        const float g0 = es0[b];
        #pragma unroll
        for (int chn = 0; chn < 16; ++chn) sn[chn] += g0 * sh_skip[b][chn];
    }
    #pragma unroll
    for (int o = 0; o < 16; ++o) {
        float a = sh_bes[o];
        #pragma unroll
        for (int chn = 0; chn < 16; ++chn) a += sn[chn] * sh_wes[chn][o];
        pb[o] = a;
    }
    const float iv = sh_iv[g];
    float vn[8][3];
    #pragma unroll
    for (int i = 0; i < 8; ++i) {
        const float f = iv * sh_lwv[i];
        vn[i][0] = p[16 + i*3 + 0] * f;
        vn[i][1] = p[16 + i*3 + 1] * f;
        vn[i][2] = p[16 + i*3 + 2] * f;
    }
    #pragma unroll
    for (int o = 0; o < 8; ++o) {
        float r0 = 0.0f, r1 = 0.0f, r2 = 0.0f;
        #pragma unroll
        for (int i = 0; i < 8; ++i) {
            const float w = sh_wev[i][o];
            r0 += vn[i][0] * w; r1 += vn[i][1] * w; r2 += vn[i][2] * w;
        }
        pb[16 + o*3 + 0] = r0;
        pb[16 + o*3 + 1] = r1;
        pb[16 + o*3 + 2] = r2;
    }
}

extern "C" void kernel_launch(void* const* d_in, const int* in_sizes, int n_in,
                              void* d_out, int out_size, void* d_ws, size_t ws_size,
                              hipStream_t stream)
{
    const float* node_fea  = (const float*)d_in[0];
    const float* edge_attr = (const float*)d_in[1];
    const int* edge_index  = (const int*)d_in[2];
    const int* xsp         = (const int*)d_in[3];
    const int* batch       = (const int*)d_in[4];
    const float* w_rh      = (const float*)d_in[5];
    const float* b_rh      = (const float*)d_in[6];
    const float* w_ro      = (const float*)d_in[7];
    const float* b_ro      = (const float*)d_in[8];
    const float* w_pre     = (const float*)d_in[9];
    const float* b_pre     = (const float*)d_in[10];
    const float* w_sc      = (const float*)d_in[11];
    const float* w_post_s  = (const float*)d_in[12];
    const float* b_post_s  = (const float*)d_in[13];
    const float* w_post_v  = (const float*)d_in[14];
    const float* ln_w_s    = (const float*)d_in[15];
    const float* ln_b_s    = (const float*)d_in[16];
    const float* ln_w_v    = (const float*)d_in[17];
    const float* w_skip    = (const float*)d_in[18];
    const float* w_edge_s  = (const float*)d_in[19];
    const float* b_edge_s  = (const float*)d_in[20];
    const float* w_edge_v  = (const float*)d_in[21];

    float* ws   = (float*)d_ws;
    int*   binv = (int*)(ws + 1056);
    float* out  = (float*)d_out;

    k_init<<<1, 1024, 0, stream>>>(ws, binv);
    k_edge_heavy<<<4096, 256, 0, stream>>>(node_fea, edge_attr, edge_index, xsp,
        w_rh, b_rh, w_ro, b_ro, w_pre, b_pre, w_sc, w_post_s, b_post_s, w_post_v,
        binv, out);
    k_stats_partial<<<256, 256, 0, stream>>>(out, edge_index, batch, ws);
    k_edge_final<<<256, 256, 0, stream>>>(out, ws, edge_attr, edge_index,
        batch, ln_w_s, ln_b_s, ln_w_v, w_skip, w_edge_s, b_edge_s, w_edge_v);

    // --- diagnostic ablations (write only ws scratch at float-offset 2048..6144) ---
    if (ws_size >= 991232) {
        float* scr = ws + 2048;
        k_abl_lm<<<8192, 256, 0, stream>>>(node_fea, edge_attr, edge_index,
            w_rh, b_rh, w_ro, b_ro, binv, scr);
        k_abl_cons<<<8192, 256, 0, stream>>>(node_fea, edge_attr, edge_index, scr);
    }
}

// Round 13
// 558.542 us; speedup vs baseline: 2.1479x; 2.1479x over previous
//
#include <hip/hip_runtime.h>

typedef unsigned short u16;
typedef unsigned int u32;
typedef __attribute__((ext_vector_type(8))) _Float16 half8;
typedef __attribute__((ext_vector_type(2))) __fp16 fp16x2;
typedef __attribute__((ext_vector_type(4))) float floatx4;

#define E_TOTAL 65536

__device__ __forceinline__ u32 pk16(float x0, float x1) {
    union { fp16x2 h; u32 u; } c;
    c.h = __builtin_amdgcn_cvt_pkrtz(x0, x1);
    return c.u;
}
union Frag8h { u32 u[4]; half8 v; };

// ws layout (floats): [0:768] per-graph stat sums; ints [1056:1088] = binv.

// ---------------- Init: zero stats + probe MFMA k-pairing (fused) ----------------
__global__ __launch_bounds__(1024) void k_init(float* __restrict__ ws, int* __restrict__ binv) {
    const int tid = threadIdx.x;
    for (int i = tid; i < 1056; i += 1024) ws[i] = 0.0f;
    if (tid < 64) {
        const int lane = tid;
        const int q = lane >> 4;
        if (lane < 32) binv[lane] = lane;    // default identity (safety)
        half8 bfr;
        #pragma unroll
        for (int j = 0; j < 8; ++j) bfr[j] = (_Float16)(float)(q*8 + j + 1);
        #pragma unroll
        for (int s = 0; s < 32; ++s) {
            const int qa = s >> 3, ja = s & 7;
            half8 afr;
            #pragma unroll
            for (int j = 0; j < 8; ++j) afr[j] = (_Float16)0.0f;
            if (q == qa) afr[ja] = (_Float16)1.0f;
            floatx4 dc = {0.0f, 0.0f, 0.0f, 0.0f};
            dc = __builtin_amdgcn_mfma_f32_16x16x32_f16(afr, bfr, dc, 0, 0, 0);
            if (lane == 0) {
                const int sB = (int)(dc[0] + 0.5f) - 1;
                if (sB >= 0 && sB < 32) binv[sB] = s;
            }
        }
    }
}

// ---------------- Kernel 1: heavy per-edge conv, 32 edges/block -----------------
// B-fragments (weights) are edge-independent: load once, feed TWO M=16 edge groups.
// Halves per-edge L2 weight traffic (the measured 80% cost, R11 ablation).
__global__ __launch_bounds__(256) void k_edge_heavy(
    const float* __restrict__ node_fea, const float* __restrict__ edge_attr,
    const int* __restrict__ edge_index, const int* __restrict__ xsp,
    const float* __restrict__ w_rh, const float* __restrict__ b_rh,
    const float* __restrict__ w_ro, const float* __restrict__ b_ro,
    const float* __restrict__ w_pre, const float* __restrict__ b_pre,
    const float* __restrict__ w_sc, const float* __restrict__ w_post_s,
    const float* __restrict__ b_post_s, const float* __restrict__ w_post_v,
    const int* __restrict__ binv,
    float* __restrict__ out)
{
    __shared__ __align__(16) u16 a_rbf[2 * 2048];    // [group][(k8*16+m)*8+j] fp16
    __shared__ __align__(16) u16 a_h[2 * 1024];      // [group][(k8*16+m)*8+j] fp16
    __shared__ __align__(16) float sh_wt[32][258];
    __shared__ float sh_sin[32][80];
    __shared__ float sh_vl[32][3][32];
    __shared__ float sh_acc[32][56];
    __shared__ float sh_es0[32][16];
    __shared__ float sh_y1[32][4];
    __shared__ int   sh_kmap[32];

    const int tid = threadIdx.x;
    const int ed = tid >> 4, l16 = tid & 15;
    const int lane = tid & 63, w = tid >> 6;
    const int quad = lane >> 4, l15 = lane & 15;
    const int e0 = blockIdx.x * 32 + ed;
    const int e1 = e0 + 16;

    if (tid < 32) sh_kmap[tid] = binv[tid];

    const int ni0 = edge_index[e0], nj0 = edge_index[E_TOTAL + e0];
    const int ni1 = edge_index[e1], nj1 = edge_index[E_TOTAL + e1];
    const float4 ea0 = *(const float4*)(edge_attr + 4*e0);
    const float4 ea1 = *(const float4*)(edge_attr + 4*e1);
    const float d0 = ea0.x, d1 = ea1.x;
    {
        const float invn0 = 1.0f / (sqrtf(ea0.y*ea0.y + ea0.z*ea0.z + ea0.w*ea0.w) + 1e-12f);
        const float invn1 = 1.0f / (sqrtf(ea1.y*ea1.y + ea1.z*ea1.z + ea1.w*ea1.w) + 1e-12f);
        if (l16 == 0) {
            sh_y1[ed][0]    = 1.7320508075688772f * ea0.y * invn0;
            sh_y1[ed][1]    = 1.7320508075688772f * ea0.z * invn0;
            sh_y1[ed][2]    = 1.7320508075688772f * ea0.w * invn0;
            sh_y1[16+ed][0] = 1.7320508075688772f * ea1.y * invn1;
            sh_y1[16+ed][1] = 1.7320508075688772f * ea1.z * invn1;
            sh_y1[16+ed][2] = 1.7320508075688772f * ea1.w * invn1;
        }
    }

    // rbf -> fp16 A-fragments for both groups
    const float C128 = -0.5f * (127.0f/6.0f) * (127.0f/6.0f);
    const float S128 = 6.0f/127.0f;
    {
        Frag8h t0, t1;
        #pragma unroll
        for (int r2 = 0; r2 < 4; ++r2) {
            const int b0i = l16*8 + 2*r2;
            const float u0 = d0 - S128 * (float)b0i;
            const float u1 = d0 - S128 * (float)(b0i + 1);
            const float v0 = d1 - S128 * (float)b0i;
            const float v1 = d1 - S128 * (float)(b0i + 1);
            t0.u[r2] = pk16(expf(C128*u0*u0), expf(C128*u1*u1));
            t1.u[r2] = pk16(expf(C128*v0*v0), expf(C128*v1*v1));
        }
        *(half8*)&a_rbf[(l16*16 + ed)*8]        = t0.v;
        *(half8*)&a_rbf[2048 + (l16*16 + ed)*8] = t1.v;
    }
    {
        const float t0 = d0 - 0.4f * (float)l16;
        const float t1 = d1 - 0.4f * (float)l16;
        sh_es0[ed][l16]    = expf(-3.125f * t0 * t0);
        sh_es0[16+ed][l16] = expf(-3.125f * t1 * t1);
    }

    const float rs80 = 0.11180339887498949f;
    const float rs32 = 0.17677669529663689f;
    {
        const float* fi = node_fea + (size_t)ni0 * 80;
        const float* fj = node_fea + (size_t)nj0 * 80;
        sh_sin[ed][2*l16+0]    = fi[2*l16+0] * rs80;
        sh_sin[ed][2*l16+1]    = fi[2*l16+1] * rs80;
        sh_sin[ed][32+2*l16+0] = fj[2*l16+0] * rs80;
        sh_sin[ed][32+2*l16+1] = fj[2*l16+1] * rs80;
        #pragma unroll
        for (int c = 0; c < 3; ++c) {
            sh_vl[ed][c][l16]      = fi[32 + 3*l16 + c] * rs32;
            sh_vl[ed][c][16 + l16] = fj[32 + 3*l16 + c] * rs32;
        }
    }
    {
        const float* fi = node_fea + (size_t)ni1 * 80;
        const float* fj = node_fea + (size_t)nj1 * 80;
        sh_sin[16+ed][2*l16+0]    = fi[2*l16+0] * rs80;
        sh_sin[16+ed][2*l16+1]    = fi[2*l16+1] * rs80;
        sh_sin[16+ed][32+2*l16+0] = fj[2*l16+0] * rs80;
        sh_sin[16+ed][32+2*l16+1] = fj[2*l16+1] * rs80;
        #pragma unroll
        for (int c = 0; c < 3; ++c) {
            sh_vl[16+ed][c][l16]      = fi[32 + 3*l16 + c] * rs32;
            sh_vl[16+ed][c][16 + l16] = fj[32 + 3*l16 + c] * rs32;
        }
    }
    for (int s = tid; s < 32*56; s += 256) (&sh_acc[0][0])[s] = 0.0f;
    __syncthreads();

    int km[8];
    u32 voff0[8], voff1[8];
    #pragma unroll
    for (int j = 0; j < 8; ++j) {
        km[j] = sh_kmap[quad*8 + j];
        voff0[j] = (u32)(km[j] * 3840 + l15);
        voff1[j] = voff0[j] + 32u * 3840u;
    }

    // edge_s + sc for both edges
    float my_sc0, my_sc1;
    {
        const int o = l16;
        float es0v = b_pre[o], sc0 = 0.0f;
        float es1v = b_pre[o], sc1 = 0.0f;
        const int p0 = 4*xsp[ni0] + xsp[nj0];
        const int p1 = 4*xsp[ni1] + xsp[nj1];
        #pragma unroll
        for (int i = 0; i < 16; ++i) {
            const float g0 = sh_es0[ed][i];
            const float g1 = sh_es0[16+ed][i];
            es0v += g0 * w_pre[i*16 + o];
            es1v += g1 * w_pre[i*16 + o];
            sc0  += g0 * w_sc[(i*16 + p0)*16 + o];
            sc1  += g1 * w_sc[(i*16 + p1)*16 + o];
        }
        sh_sin[ed][64 + o]    = es0v * rs80;
        sh_sin[16+ed][64 + o] = es1v * rs80;
        my_sc0 = sc0 * 0.0625f;
        my_sc1 = sc1 * 0.0625f;
    }

    // h = silu(rbf @ w_rh + b_rh), both groups share B
    {
        floatx4 h0 = {0.0f, 0.0f, 0.0f, 0.0f};
        floatx4 h1 = {0.0f, 0.0f, 0.0f, 0.0f};
        #pragma unroll
        for (int kk = 0; kk < 4; ++kk) {
            const half8 ag0 = *(const half8*)&a_rbf[((kk*4 + quad)*16 + l15)*8];
            const half8 ag1 = *(const half8*)&a_rbf[2048 + ((kk*4 + quad)*16 + l15)*8];
            Frag8h bh;
            #pragma unroll
            for (int jj = 0; jj < 4; ++jj) {
                const float x0 = w_rh[(size_t)(kk*32 + km[2*jj+0])*64 + w*16 + l15];
                const float x1 = w_rh[(size_t)(kk*32 + km[2*jj+1])*64 + w*16 + l15];
                bh.u[jj] = pk16(x0, x1);
            }
            h0 = __builtin_amdgcn_mfma_f32_16x16x32_f16(ag0, bh.v, h0, 0, 0, 0);
            h1 = __builtin_amdgcn_mfma_f32_16x16x32_f16(ag1, bh.v, h1, 0, 0, 0);
        }
        const int hn = w*16 + l15;
        const float bb = b_rh[hn];
        const int k8 = hn >> 3, j2 = hn & 7;
        #pragma unroll
        for (int r = 0; r < 4; ++r) {
            const int m = quad*4 + r;
            {
                const float x = h0[r] + bb;
                const float s = x / (1.0f + expf(-x));
                union { _Float16 h; u16 u; } cv; cv.h = (_Float16)s;
                a_h[(k8*16 + m)*8 + j2] = cv.u;
            }
            {
                const float x = h1[r] + bb;
                const float s = x / (1.0f + expf(-x));
                union { _Float16 h; u16 u; } cv; cv.h = (_Float16)s;
                a_h[1024 + (k8*16 + m)*8 + j2] = cv.u;
            }
        }
    }
    __syncthreads();

    const half8 a0g0 = *(const half8*)&a_h[((0*4 + quad)*16 + l15)*8];
    const half8 a1g0 = *(const half8*)&a_h[((1*4 + quad)*16 + l15)*8];
    const half8 a0g1 = *(const half8*)&a_h[1024 + ((0*4 + quad)*16 + l15)*8];
    const half8 a1g1 = *(const half8*)&a_h[1024 + ((1*4 + quad)*16 + l15)*8];

    // -------- main loop: 15 chunks of 256 cols; one B-load feeds both edge groups ----
    for (int ch = 0; ch < 15; ++ch) {
        const int coff = ch * 256;
        floatx4 acc0[4], acc1[4];
        float bias[4];
        #pragma unroll
        for (int ct = 0; ct < 4; ++ct) {
            const int sgct = __builtin_amdgcn_readfirstlane(ch*16 + w*4 + ct);
            const float* bp = w_ro + sgct*16;
            float f0[8], f1[8];
            #pragma unroll
            for (int j = 0; j < 8; ++j) {
                f0[j] = bp[voff0[j]];
                f1[j] = bp[voff1[j]];
            }
            Frag8h b0, b1;
            #pragma unroll
            for (int jj = 0; jj < 4; ++jj) {
                b0.u[jj] = pk16(f0[2*jj], f0[2*jj+1]);
                b1.u[jj] = pk16(f1[2*jj], f1[2*jj+1]);
            }
            floatx4 a = {0.0f, 0.0f, 0.0f, 0.0f};
            a = __builtin_amdgcn_mfma_f32_16x16x32_f16(a0g0, b0.v, a, 0, 0, 0);
            a = __builtin_amdgcn_mfma_f32_16x16x32_f16(a1g0, b1.v, a, 0, 0, 0);
            acc0[ct] = a;
            floatx4 c = {0.0f, 0.0f, 0.0f, 0.0f};
            c = __builtin_amdgcn_mfma_f32_16x16x32_f16(a0g1, b0.v, c, 0, 0, 0);
            c = __builtin_amdgcn_mfma_f32_16x16x32_f16(a1g1, b1.v, c, 0, 0, 0);
            acc1[ct] = c;
            bias[ct] = b_ro[sgct*16 + l15];
        }
        __syncthreads();
        #pragma unroll
        for (int ct = 0; ct < 4; ++ct) {
            const int col = w*64 + ct*16 + l15;
            #pragma unroll
            for (int r = 0; r < 4; ++r) {
                sh_wt[quad*4 + r][col]      = acc0[ct][r] + bias[ct];
                sh_wt[16 + quad*4 + r][col] = acc1[ct][r] + bias[ct];
            }
        }
        __syncthreads();

        if (ch <= 7) {
            const int hi = (ch == 7) ? 1920 : (coff + 256);
            for (int idx = tid; idx < 768; idx += 256) {
                const int eo = idx / 24, o = idx % 24;
                const int i0 = (coff > o) ? (coff - o + 23) / 24 : 0;
                int i1 = (hi - o + 23) / 24; if (i1 > 80) i1 = 80;
                float a = 0.0f;
                for (int i = i0; i < i1; ++i)
                    a += sh_sin[eo][i] * sh_wt[eo][i*24 + o - coff];
                sh_acc[eo][o] += a;
            }
        }
        if (ch == 7) {
            for (int idx = tid; idx < 256; idx += 256) {
                const int eo = idx >> 3, o = idx & 7;
                float a = 0.0f;
                #pragma unroll
                for (int i = 0; i < 16; ++i)
                    a += sh_sin[eo][i] * sh_wt[eo][128 + i*8 + o];
                sh_acc[eo][24 + o] += a;
            }
        }
        if (ch == 8 || ch == 9) {
            const int ib = (ch == 8) ? 16 : 48;
            for (int idx = tid; idx < 256; idx += 256) {
                const int eo = idx >> 3, o = idx & 7;
                float a = 0.0f;
                #pragma unroll
                for (int i2 = 0; i2 < 32; ++i2)
                    a += sh_sin[eo][ib + i2] * sh_wt[eo][i2*8 + o];
                sh_acc[eo][24 + o] += a;
            }
        }
        if (ch == 10) {
            for (int idx = tid; idx < 768; idx += 256) {
                const int eo = idx / 24, rem = idx % 24;
                const int o = rem / 3, cc = rem % 3;
                float a = 0.0f;
                #pragma unroll
                for (int i = 0; i < 32; ++i)
                    a += sh_vl[eo][cc][i] * sh_wt[eo][i*8 + o];
                sh_acc[eo][32 + o*3 + cc] += a;
            }
        }
        if (ch >= 11 && ch <= 13) {
            const int rel = coff - 2816;
            for (int idx = tid; idx < 768; idx += 256) {
                const int eo = idx / 24, o = idx % 24;
                const int i0 = (rel > o) ? (rel - o + 23) / 24 : 0;
                int i1 = (rel + 256 - o + 23) / 24; if (i1 > 32) i1 = 32;
                const float Ya = sh_y1[eo][0], Yb = sh_y1[eo][1], Yc = sh_y1[eo][2];
                float a = 0.0f;
                for (int i = i0; i < i1; ++i) {
                    const float qv = sh_vl[eo][0][i]*Ya + sh_vl[eo][1][i]*Yb
                                   + sh_vl[eo][2][i]*Yc;
                    a += qv * sh_wt[eo][i*24 + o - rel];
                }
                sh_acc[eo][o] += a * 0.57735026918962573f;
            }
        }
        if (ch == 14) {
            for (int idx = tid; idx < 768; idx += 256) {
                const int eo = idx / 24, rem = idx % 24;
                const int o = rem / 3, cc = rem % 3;
                const int c1 = (cc < 2) ? cc + 1 : 0;
                const int c2 = (c1 < 2) ? c1 + 1 : 0;
                const float Yp = sh_y1[eo][c2];
                const float Ym = sh_y1[eo][c1];
                float a = 0.0f;
                #pragma unroll
                for (int i = 0; i < 32; ++i)
                    a += (sh_vl[eo][c1][i]*Yp - sh_vl[eo][c2][i]*Ym) * sh_wt[eo][i*8 + o];
                sh_acc[eo][32 + o*3 + cc] += a * 0.70710678118654746f;
            }
        }
    }
    __syncthreads();

    // -------- epilogue: both edges --------
    #pragma unroll
    for (int g = 0; g < 2; ++g) {
        const int er = g*16 + ed;
        const int e  = (g == 0) ? e0 : e1;
        const float msc = (g == 0) ? my_sc0 : my_sc1;
        {
            const int o = l16;
            float a = b_post_s[o] + msc;
            #pragma unroll
            for (int i = 0; i < 16; ++i) {
                const float sv = sh_acc[er][i];
                a += (sv / (1.0f + expf(-sv))) * w_post_s[i*16 + o];
            }
            out[(size_t)e*40 + o] = a;
        }
        if (l16 < 8) {
            const int o = l16;
            const float Ya = sh_y1[er][0], Yb = sh_y1[er][1], Yc = sh_y1[er][2];
            float r0 = 0.0f, r1 = 0.0f, r2 = 0.0f;
            #pragma unroll
            for (int i = 0; i < 8; ++i) {
                const float gt = 1.0f / (1.0f + expf(-sh_acc[er][16 + i]));
                const float a2 = sh_acc[er][24 + i];
                const float ww = w_post_v[i*8 + o];
                r0 += (a2*Ya + sh_acc[er][32 + i*3 + 0]) * gt * ww;
                r1 += (a2*Yb + sh_acc[er][32 + i*3 + 1]) * gt * ww;
                r2 += (a2*Yc + sh_acc[er][32 + i*3 + 2]) * gt * ww;
            }
            out[(size_t)e*40 + 16 + o*3 + 0] = r0;
            out[(size_t)e*40 + 16 + o*3 + 1] = r1;
            out[(size_t)e*40 + 16 + o*3 + 2] = r2;
        }
    }
}

// ---------------- Kernel 2a: per-edge LDS-atomic segment stats ----------------------
__global__ __launch_bounds__(256) void k_stats_partial(
    const float* __restrict__ sv, const int* __restrict__ edge_index,
    const int* __restrict__ batch, float* __restrict__ ws)
{
    __shared__ float bins[768];
    const int tid = threadIdx.x;
    for (int s = tid; s < 768; s += 256) bins[s] = 0.0f;
    __syncthreads();

    const int e = blockIdx.x * 256 + tid;
    const int g = batch[edge_index[e]];
    const float* p = sv + (size_t)e * 40;
    float v[40];
    #pragma unroll
    for (int j = 0; j < 40; ++j) v[j] = p[j];

    float* bg = bins + g * 48;
    #pragma unroll
    for (int chn = 0; chn < 16; ++chn) {
        atomicAdd(&bg[chn],      v[chn]);
        atomicAdd(&bg[16 + chn], v[chn] * v[chn]);
    }
    #pragma unroll
    for (int o = 0; o < 8; ++o) {
        const float a = v[16 + o*3], b = v[16 + o*3 + 1], c = v[16 + o*3 + 2];
        atomicAdd(&bg[32 + o], a*a + b*b + c*c);
    }
    atomicAdd(&bg[40], 1.0f);
    __syncthreads();

    for (int s = tid; s < 768; s += 256) {
        const float x = bins[s];
        if (x != 0.0f) atomicAdd(&ws[s], x);
    }
}

// ---------------- Kernel 4: stats-finalize (folded) + LN + skip + edge projections --
__global__ __launch_bounds__(256) void k_edge_final(
    float* buf, const float* __restrict__ ws,
    const float* __restrict__ edge_attr, const int* __restrict__ edge_index,
    const int* __restrict__ batch,
    const float* __restrict__ ln_w_s, const float* __restrict__ ln_b_s,
    const float* __restrict__ ln_w_v, const float* __restrict__ w_skip,
    const float* __restrict__ w_edge_s, const float* __restrict__ b_edge_s,
    const float* __restrict__ w_edge_v)
{
    __shared__ float sh_mu[16][16];
    __shared__ float sh_is[16], sh_iv[16];
    __shared__ float sh_lws[16], sh_lbs[16], sh_lwv[8];
    __shared__ float sh_skip[16][16], sh_wes[16][16], sh_bes[16], sh_wev[8][8];
    const int tid = threadIdx.x;
    if (tid < 16) {
        const int g = tid;
        float cnt = ws[g*48 + 40]; if (cnt < 1.0f) cnt = 1.0f;
        const float ic = 1.0f / cnt;
        float vs = 0.0f;
        for (int chn = 0; chn < 16; ++chn) {
            const float mu = ws[g*48 + chn] * ic;
            sh_mu[g][chn] = mu;
            vs += ws[g*48 + 16 + chn] * ic - mu * mu;
        }
        if (vs < 0.0f) vs = 0.0f;
        sh_is[g] = 1.0f / sqrtf(vs * (1.0f/16.0f) + 1e-5f);
        float vv = 0.0f;
        for (int o = 0; o < 8; ++o) vv += ws[g*48 + 32 + o];
        vv = vv * ic * (1.0f/3.0f) * (1.0f/8.0f);
        sh_iv[g] = 1.0f / sqrtf(vv + 1e-5f);
    }
    sh_skip[tid >> 4][tid & 15] = w_skip[tid];
    sh_wes[tid >> 4][tid & 15]  = w_edge_s[tid];
    if (tid < 16) {
        sh_lws[tid] = ln_w_s[tid];
        sh_lbs[tid] = ln_b_s[tid];
        sh_bes[tid] = b_edge_s[tid];
    }
    if (tid < 8)  sh_lwv[tid] = ln_w_v[tid];
    if (tid < 64) sh_wev[tid >> 3][tid & 7] = w_edge_v[tid];
    __syncthreads();

    const int e = blockIdx.x * 256 + tid;
    const int g = batch[edge_index[e]];
    const float d = edge_attr[4*e];
    float es0[16];
    #pragma unroll
    for (int b = 0; b < 16; ++b) {
        const float t = d - 0.4f * (float)b;
        es0[b] = expf(-3.125f * t * t);
    }
    float p[40];
    float* pb = buf + (size_t)e * 40;
    #pragma unroll
    for (int j = 0; j < 40; ++j) p[j] = pb[j];

    const float is = sh_is[g];
    float sn[16];
    #pragma unroll
    for (int chn = 0; chn < 16; ++chn)
        sn[chn] = (p[chn] - sh_mu[g][chn]) * is * sh_lws[chn] + sh_lbs[chn];
    #pragma unroll
    for (int b = 0; b < 16; ++b) {
        const float g0 = es0[b];
        #pragma unroll
        for (int chn = 0; chn < 16; ++chn) sn[chn] += g0 * sh_skip[b][chn];
    }
    #pragma unroll
    for (int o = 0; o < 16; ++o) {
        float a = sh_bes[o];
        #pragma unroll
        for (int chn = 0; chn < 16; ++chn) a += sn[chn] * sh_wes[chn][o];
        pb[o] = a;
    }
    const float iv = sh_iv[g];
    float vn[8][3];
    #pragma unroll
    for (int i = 0; i < 8; ++i) {
        const float f = iv * sh_lwv[i];
        vn[i][0] = p[16 + i*3 + 0] * f;
        vn[i][1] = p[16 + i*3 + 1] * f;
        vn[i][2] = p[16 + i*3 + 2] * f;
    }
    #pragma unroll
    for (int o = 0; o < 8; ++o) {
        float r0 = 0.0f, r1 = 0.0f, r2 = 0.0f;
        #pragma unroll
        for (int i = 0; i < 8; ++i) {
            const float w = sh_wev[i][o];
            r0 += vn[i][0] * w; r1 += vn[i][1] * w; r2 += vn[i][2] * w;
        }
        pb[16 + o*3 + 0] = r0;
        pb[16 + o*3 + 1] = r1;
        pb[16 + o*3 + 2] = r2;
    }
}

extern "C" void kernel_launch(void* const* d_in, const int* in_sizes, int n_in,
                              void* d_out, int out_size, void* d_ws, size_t ws_size,
                              hipStream_t stream)
{
    const float* node_fea  = (const float*)d_in[0];
    const float* edge_attr = (const float*)d_in[1];
    const int* edge_index  = (const int*)d_in[2];
    const int* xsp         = (const int*)d_in[3];
    const int* batch       = (const int*)d_in[4];
    const float* w_rh      = (const float*)d_in[5];
    const float* b_rh      = (const float*)d_in[6];
    const float* w_ro      = (const float*)d_in[7];
    const float* b_ro      = (const float*)d_in[8];
    const float* w_pre     = (const float*)d_in[9];
    const float* b_pre     = (const float*)d_in[10];
    const float* w_sc      = (const float*)d_in[11];
    const float* w_post_s  = (const float*)d_in[12];
    const float* b_post_s  = (const float*)d_in[13];
    const float* w_post_v  = (const float*)d_in[14];
    const float* ln_w_s    = (const float*)d_in[15];
    const float* ln_b_s    = (const float*)d_in[16];
    const float* ln_w_v    = (const float*)d_in[17];
    const float* w_skip    = (const float*)d_in[18];
    const float* w_edge_s  = (const float*)d_in[19];
    const float* b_edge_s  = (const float*)d_in[20];
    const float* w_edge_v  = (const float*)d_in[21];

    float* ws   = (float*)d_ws;
    int*   binv = (int*)(ws + 1056);
    float* out  = (float*)d_out;

    k_init<<<1, 1024, 0, stream>>>(ws, binv);
    k_edge_heavy<<<2048, 256, 0, stream>>>(node_fea, edge_attr, edge_index, xsp,
        w_rh, b_rh, w_ro, b_ro, w_pre, b_pre, w_sc, w_post_s, b_post_s, w_post_v,
        binv, out);
    k_stats_partial<<<256, 256, 0, stream>>>(out, edge_index, batch, ws);
    k_edge_final<<<256, 256, 0, stream>>>(out, ws, edge_attr, edge_index,
        batch, ln_w_s, ln_b_s, ln_w_v, w_skip, w_edge_s, b_edge_s, w_edge_v);
}

// Round 14
// 431.819 us; speedup vs baseline: 2.7782x; 1.2935x over previous
//
#include <hip/hip_runtime.h>

typedef unsigned short u16;
typedef unsigned int u32;
typedef __attribute__((ext_vector_type(8))) _Float16 half8;
typedef __attribute__((ext_vector_type(2))) __fp16 fp16x2;
typedef __attribute__((ext_vector_type(4))) float floatx4;

#define E_TOTAL 65536

__device__ __forceinline__ u32 pk16(float x0, float x1) {
    union { fp16x2 h; u32 u; } c;
    c.h = __builtin_amdgcn_cvt_pkrtz(x0, x1);
    return c.u;
}
union Frag8h { u32 u[4]; half8 v; };

// ws layout (floats): [0:768] per-graph stat sums; ints [1056:1088] = binv.

// ---------------- Init: zero stats + probe MFMA k-pairing (fused) ----------------
__global__ __launch_bounds__(1024) void k_init(float* __restrict__ ws, int* __restrict__ binv) {
    const int tid = threadIdx.x;
    for (int i = tid; i < 1056; i += 1024) ws[i] = 0.0f;
    if (tid < 64) {
        const int lane = tid;
        const int q = lane >> 4;
        if (lane < 32) binv[lane] = lane;    // default identity (safety)
        half8 bfr;
        #pragma unroll
        for (int j = 0; j < 8; ++j) bfr[j] = (_Float16)(float)(q*8 + j + 1);
        #pragma unroll
        for (int s = 0; s < 32; ++s) {
            const int qa = s >> 3, ja = s & 7;
            half8 afr;
            #pragma unroll
            for (int j = 0; j < 8; ++j) afr[j] = (_Float16)0.0f;
            if (q == qa) afr[ja] = (_Float16)1.0f;
            floatx4 dc = {0.0f, 0.0f, 0.0f, 0.0f};
            dc = __builtin_amdgcn_mfma_f32_16x16x32_f16(afr, bfr, dc, 0, 0, 0);
            if (lane == 0) {
                const int sB = (int)(dc[0] + 0.5f) - 1;
                if (sB >= 0 && sB < 32) binv[sB] = s;
            }
        }
    }
}

// ---------------- Kernel 1: heavy conv, 32 edges/block, 128-col chunks, overlay ----
// R13 halved weight traffic but dropped to 1 block/CU (LDS 77.8KB). This keeps the
// traffic halving and restores 3 blocks/CU: sh_wt half-width (30 chunks x 128 cols)
// + prologue buffers (a_rbf/a_h/es0) OVERLAID on sh_wt (they die before 1st wt write).
// LDS: 47.0 KB.
__global__ __launch_bounds__(256) void k_edge_heavy(
    const float* __restrict__ node_fea, const float* __restrict__ edge_attr,
    const int* __restrict__ edge_index, const int* __restrict__ xsp,
    const float* __restrict__ w_rh, const float* __restrict__ b_rh,
    const float* __restrict__ w_ro, const float* __restrict__ b_ro,
    const float* __restrict__ w_pre, const float* __restrict__ b_pre,
    const float* __restrict__ w_sc, const float* __restrict__ w_post_s,
    const float* __restrict__ b_post_s, const float* __restrict__ w_post_v,
    const int* __restrict__ binv,
    float* __restrict__ out)
{
    __shared__ __align__(16) float sh_wt[32][130];   // 16640 B; prologue overlays here
    __shared__ float sh_sin[32][80];
    __shared__ float sh_vl[32][3][32];
    __shared__ float sh_acc[32][56];
    __shared__ float sh_y1[32][4];
    __shared__ int   sh_kmap[32];

    // Overlay (all dead before first sh_wt write; mutually disjoint):
    u16*   a_rbf = (u16*)&sh_wt[0][0];                     // [0,8192) B : 2 groups x 2048 u16
    u16*   a_h   = (u16*)((char*)&sh_wt[0][0] + 8192);     // [8192,12288) B
    float* es0f  = (float*)((char*)&sh_wt[0][0] + 12288);  // [12288,14336) B : 32x16 f32

    const int tid = threadIdx.x;
    const int ed = tid >> 4, l16 = tid & 15;
    const int lane = tid & 63, w = tid >> 6;
    const int quad = lane >> 4, l15 = lane & 15;
    const int e0 = blockIdx.x * 32 + ed;
    const int e1 = e0 + 16;

    if (tid < 32) sh_kmap[tid] = binv[tid];

    const int ni0 = edge_index[e0], nj0 = edge_index[E_TOTAL + e0];
    const int ni1 = edge_index[e1], nj1 = edge_index[E_TOTAL + e1];
    const float4 ea0 = *(const float4*)(edge_attr + 4*e0);
    const float4 ea1 = *(const float4*)(edge_attr + 4*e1);
    const float d0 = ea0.x, d1 = ea1.x;
    {
        const float invn0 = 1.0f / (sqrtf(ea0.y*ea0.y + ea0.z*ea0.z + ea0.w*ea0.w) + 1e-12f);
        const float invn1 = 1.0f / (sqrtf(ea1.y*ea1.y + ea1.z*ea1.z + ea1.w*ea1.w) + 1e-12f);
        if (l16 == 0) {
            sh_y1[ed][0]    = 1.7320508075688772f * ea0.y * invn0;
            sh_y1[ed][1]    = 1.7320508075688772f * ea0.z * invn0;
            sh_y1[ed][2]    = 1.7320508075688772f * ea0.w * invn0;
            sh_y1[16+ed][0] = 1.7320508075688772f * ea1.y * invn1;
            sh_y1[16+ed][1] = 1.7320508075688772f * ea1.z * invn1;
            sh_y1[16+ed][2] = 1.7320508075688772f * ea1.w * invn1;
        }
    }

    // rbf -> fp16 A-fragments for both groups (into overlay)
    const float C128 = -0.5f * (127.0f/6.0f) * (127.0f/6.0f);
    const float S128 = 6.0f/127.0f;
    {
        Frag8h t0, t1;
        #pragma unroll
        for (int r2 = 0; r2 < 4; ++r2) {
            const int b0i = l16*8 + 2*r2;
            const float u0 = d0 - S128 * (float)b0i;
            const float u1 = d0 - S128 * (float)(b0i + 1);
            const float v0 = d1 - S128 * (float)b0i;
            const float v1 = d1 - S128 * (float)(b0i + 1);
            t0.u[r2] = pk16(expf(C128*u0*u0), expf(C128*u1*u1));
            t1.u[r2] = pk16(expf(C128*v0*v0), expf(C128*v1*v1));
        }
        *(half8*)&a_rbf[(l16*16 + ed)*8]        = t0.v;
        *(half8*)&a_rbf[2048 + (l16*16 + ed)*8] = t1.v;
    }
    {
        const float t0 = d0 - 0.4f * (float)l16;
        const float t1 = d1 - 0.4f * (float)l16;
        es0f[ed*16 + l16]      = expf(-3.125f * t0 * t0);
        es0f[(16+ed)*16 + l16] = expf(-3.125f * t1 * t1);
    }

    const float rs80 = 0.11180339887498949f;
    const float rs32 = 0.17677669529663689f;
    {
        const float* fi = node_fea + (size_t)ni0 * 80;
        const float* fj = node_fea + (size_t)nj0 * 80;
        sh_sin[ed][2*l16+0]    = fi[2*l16+0] * rs80;
        sh_sin[ed][2*l16+1]    = fi[2*l16+1] * rs80;
        sh_sin[ed][32+2*l16+0] = fj[2*l16+0] * rs80;
        sh_sin[ed][32+2*l16+1] = fj[2*l16+1] * rs80;
        #pragma unroll
        for (int c = 0; c < 3; ++c) {
            sh_vl[ed][c][l16]      = fi[32 + 3*l16 + c] * rs32;
            sh_vl[ed][c][16 + l16] = fj[32 + 3*l16 + c] * rs32;
        }
    }
    {
        const float* fi = node_fea + (size_t)ni1 * 80;
        const float* fj = node_fea + (size_t)nj1 * 80;
        sh_sin[16+ed][2*l16+0]    = fi[2*l16+0] * rs80;
        sh_sin[16+ed][2*l16+1]    = fi[2*l16+1] * rs80;
        sh_sin[16+ed][32+2*l16+0] = fj[2*l16+0] * rs80;
        sh_sin[16+ed][32+2*l16+1] = fj[2*l16+1] * rs80;
        #pragma unroll
        for (int c = 0; c < 3; ++c) {
            sh_vl[16+ed][c][l16]      = fi[32 + 3*l16 + c] * rs32;
            sh_vl[16+ed][c][16 + l16] = fj[32 + 3*l16 + c] * rs32;
        }
    }
    for (int s = tid; s < 32*56; s += 256) (&sh_acc[0][0])[s] = 0.0f;
    __syncthreads();

    int km[8];
    u32 voff0[8], voff1[8];
    #pragma unroll
    for (int j = 0; j < 8; ++j) {
        km[j] = sh_kmap[quad*8 + j];
        voff0[j] = (u32)(km[j] * 3840 + l15);
        voff1[j] = voff0[j] + 32u * 3840u;
    }

    // edge_s + sc for both edges (reads es0f overlay)
    float my_sc0, my_sc1;
    {
        const int o = l16;
        float es0v = b_pre[o], sc0 = 0.0f;
        float es1v = b_pre[o], sc1 = 0.0f;
        const int p0 = 4*xsp[ni0] + xsp[nj0];
        const int p1 = 4*xsp[ni1] + xsp[nj1];
        #pragma unroll
        for (int i = 0; i < 16; ++i) {
            const float g0 = es0f[ed*16 + i];
            const float g1 = es0f[(16+ed)*16 + i];
            es0v += g0 * w_pre[i*16 + o];
            es1v += g1 * w_pre[i*16 + o];
            sc0  += g0 * w_sc[(i*16 + p0)*16 + o];
            sc1  += g1 * w_sc[(i*16 + p1)*16 + o];
        }
        sh_sin[ed][64 + o]    = es0v * rs80;
        sh_sin[16+ed][64 + o] = es1v * rs80;
        my_sc0 = sc0 * 0.0625f;
        my_sc1 = sc1 * 0.0625f;
    }

    // h = silu(rbf @ w_rh + b_rh), both groups share B  (reads a_rbf, writes a_h)
    {
        floatx4 h0 = {0.0f, 0.0f, 0.0f, 0.0f};
        floatx4 h1 = {0.0f, 0.0f, 0.0f, 0.0f};
        #pragma unroll
        for (int kk = 0; kk < 4; ++kk) {
            const half8 ag0 = *(const half8*)&a_rbf[((kk*4 + quad)*16 + l15)*8];
            const half8 ag1 = *(const half8*)&a_rbf[2048 + ((kk*4 + quad)*16 + l15)*8];
            Frag8h bh;
            #pragma unroll
            for (int jj = 0; jj < 4; ++jj) {
                const float x0 = w_rh[(size_t)(kk*32 + km[2*jj+0])*64 + w*16 + l15];
                const float x1 = w_rh[(size_t)(kk*32 + km[2*jj+1])*64 + w*16 + l15];
                bh.u[jj] = pk16(x0, x1);
            }
            h0 = __builtin_amdgcn_mfma_f32_16x16x32_f16(ag0, bh.v, h0, 0, 0, 0);
            h1 = __builtin_amdgcn_mfma_f32_16x16x32_f16(ag1, bh.v, h1, 0, 0, 0);
        }
        const int hn = w*16 + l15;
        const float bb = b_rh[hn];
        const int k8 = hn >> 3, j2 = hn & 7;
        #pragma unroll
        for (int r = 0; r < 4; ++r) {
            const int m = quad*4 + r;
            {
                const float x = h0[r] + bb;
                const float s = x / (1.0f + expf(-x));
                union { _Float16 h; u16 u; } cv; cv.h = (_Float16)s;
                a_h[(k8*16 + m)*8 + j2] = cv.u;
            }
            {
                const float x = h1[r] + bb;
                const float s = x / (1.0f + expf(-x));
                union { _Float16 h; u16 u; } cv; cv.h = (_Float16)s;
                a_h[1024 + (k8*16 + m)*8 + j2] = cv.u;
            }
        }
    }
    __syncthreads();

    // A-fragments into registers (overlay dies after this point)
    const half8 a0g0 = *(const half8*)&a_h[((0*4 + quad)*16 + l15)*8];
    const half8 a1g0 = *(const half8*)&a_h[((1*4 + quad)*16 + l15)*8];
    const half8 a0g1 = *(const half8*)&a_h[1024 + ((0*4 + quad)*16 + l15)*8];
    const half8 a1g1 = *(const half8*)&a_h[1024 + ((1*4 + quad)*16 + l15)*8];

    // -------- main loop: 30 chunks x 128 cols; wave w -> cols [w*32, w*32+32) --------
    for (int ch = 0; ch < 30; ++ch) {
        const int coff = ch * 128;
        floatx4 acc0[2], acc1[2];
        float bias[2];
        #pragma unroll
        for (int ct = 0; ct < 2; ++ct) {
            const int sgct = __builtin_amdgcn_readfirstlane(ch*8 + w*2 + ct); // wave-uniform
            const float* bp = w_ro + sgct*16;
            float f0[8], f1[8];
            #pragma unroll
            for (int j = 0; j < 8; ++j) {
                f0[j] = bp[voff0[j]];
                f1[j] = bp[voff1[j]];
            }
            Frag8h b0, b1;
            #pragma unroll
            for (int jj = 0; jj < 4; ++jj) {
                b0.u[jj] = pk16(f0[2*jj], f0[2*jj+1]);
                b1.u[jj] = pk16(f1[2*jj], f1[2*jj+1]);
            }
            floatx4 a = {0.0f, 0.0f, 0.0f, 0.0f};
            a = __builtin_amdgcn_mfma_f32_16x16x32_f16(a0g0, b0.v, a, 0, 0, 0);
            a = __builtin_amdgcn_mfma_f32_16x16x32_f16(a1g0, b1.v, a, 0, 0, 0);
            acc0[ct] = a;
            floatx4 c = {0.0f, 0.0f, 0.0f, 0.0f};
            c = __builtin_amdgcn_mfma_f32_16x16x32_f16(a0g1, b0.v, c, 0, 0, 0);
            c = __builtin_amdgcn_mfma_f32_16x16x32_f16(a1g1, b1.v, c, 0, 0, 0);
            acc1[ct] = c;
            bias[ct] = b_ro[sgct*16 + l15];
        }
        __syncthreads();   // previous chunk's consumers done with sh_wt
        #pragma unroll
        for (int ct = 0; ct < 2; ++ct) {
            const int col = w*32 + ct*16 + l15;
            #pragma unroll
            for (int r = 0; r < 4; ++r) {
                sh_wt[quad*4 + r][col]      = acc0[ct][r] + bias[ct];
                sh_wt[16 + quad*4 + r][col] = acc1[ct][r] + bias[ct];
            }
        }
        __syncthreads();

        if (ch < 15) {          // w1: cols 0..1920, 24-wide -> s_conv (dynamic bounds)
            for (int idx = tid; idx < 768; idx += 256) {
                const int eo = idx / 24, o = idx % 24;
                const int i0 = (coff > o) ? (coff - o + 23) / 24 : 0;
                int i1 = (coff + 128 - o + 23) / 24; if (i1 > 80) i1 = 80;
                float a = 0.0f;
                for (int i = i0; i < i1; ++i)
                    a += sh_sin[eo][i] * sh_wt[eo][i*24 + o - coff];
                sh_acc[eo][o] += a;
            }
        } else if (ch < 20) {   // w2: 16 rows x 8 per chunk (STATIC)
            const int ib = (ch - 15) * 16;
            for (int idx = tid; idx < 256; idx += 256) {
                const int eo = idx >> 3, o = idx & 7;
                float a = 0.0f;
                #pragma unroll
                for (int i = 0; i < 16; ++i)
                    a += sh_sin[eo][ib + i] * sh_wt[eo][i*8 + o];
                sh_acc[eo][24 + o] += a;
            }
        } else if (ch < 22) {   // w3: 16 rows x 8 per chunk, left = v_in[:,c] (STATIC)
            const int ib = (ch - 20) * 16;
            for (int idx = tid; idx < 768; idx += 256) {
                const int eo = idx / 24, rem = idx % 24;
                const int o = rem / 3, cc = rem % 3;
                float a = 0.0f;
                #pragma unroll
                for (int i = 0; i < 16; ++i)
                    a += sh_vl[eo][cc][ib + i] * sh_wt[eo][i*8 + o];
                sh_acc[eo][32 + o*3 + cc] += a;
            }
        } else if (ch < 28) {   // w4: cols 2816..3584, 24-wide, q inline (dynamic)
            const int rel = coff - 2816;
            for (int idx = tid; idx < 768; idx += 256) {
                const int eo = idx / 24, o = idx % 24;
                const int i0 = (rel > o) ? (rel - o + 23) / 24 : 0;
                int i1 = (rel + 128 - o + 23) / 24; if (i1 > 32) i1 = 32;
                const float Ya = sh_y1[eo][0], Yb = sh_y1[eo][1], Yc = sh_y1[eo][2];
                float a = 0.0f;
                for (int i = i0; i < i1; ++i) {
                    const float qv = sh_vl[eo][0][i]*Ya + sh_vl[eo][1][i]*Yb
                                   + sh_vl[eo][2][i]*Yc;
                    a += qv * sh_wt[eo][i*24 + o - rel];
                }
                sh_acc[eo][o] += a * 0.57735026918962573f;
            }
        } else {                // w5: 16 rows x 8 per chunk, cross inline (STATIC)
            const int ib = (ch - 28) * 16;
            for (int idx = tid; idx < 768; idx += 256) {
                const int eo = idx / 24, rem = idx % 24;
                const int o = rem / 3, cc = rem % 3;
                const int c1 = (cc < 2) ? cc + 1 : 0;
                const int c2 = (c1 < 2) ? c1 + 1 : 0;
                const float Yp = sh_y1[eo][c2];
                const float Ym = sh_y1[eo][c1];
                float a = 0.0f;
                #pragma unroll
                for (int i = 0; i < 16; ++i)
                    a += (sh_vl[eo][c1][ib+i]*Yp - sh_vl[eo][c2][ib+i]*Ym) * sh_wt[eo][i*8 + o];
                sh_acc[eo][32 + o*3 + cc] += a * 0.70710678118654746f;
            }
        }
    }
    __syncthreads();

    // -------- epilogue: both edges --------
    #pragma unroll
    for (int g = 0; g < 2; ++g) {
        const int er = g*16 + ed;
        const int e  = (g == 0) ? e0 : e1;
        const float msc = (g == 0) ? my_sc0 : my_sc1;
        {
            const int o = l16;
            float a = b_post_s[o] + msc;
            #pragma unroll
            for (int i = 0; i < 16; ++i) {
                const float sv = sh_acc[er][i];
                a += (sv / (1.0f + expf(-sv))) * w_post_s[i*16 + o];
            }
            out[(size_t)e*40 + o] = a;
        }
        if (l16 < 8) {
            const int o = l16;
            const float Ya = sh_y1[er][0], Yb = sh_y1[er][1], Yc = sh_y1[er][2];
            float r0 = 0.0f, r1 = 0.0f, r2 = 0.0f;
            #pragma unroll
            for (int i = 0; i < 8; ++i) {
                const float gt = 1.0f / (1.0f + expf(-sh_acc[er][16 + i]));
                const float a2 = sh_acc[er][24 + i];
                const float ww = w_post_v[i*8 + o];
                r0 += (a2*Ya + sh_acc[er][32 + i*3 + 0]) * gt * ww;
                r1 += (a2*Yb + sh_acc[er][32 + i*3 + 1]) * gt * ww;
                r2 += (a2*Yc + sh_acc[er][32 + i*3 + 2]) * gt * ww;
            }
            out[(size_t)e*40 + 16 + o*3 + 0] = r0;
            out[(size_t)e*40 + 16 + o*3 + 1] = r1;
            out[(size_t)e*40 + 16 + o*3 + 2] = r2;
        }
    }
}

// ---------------- Kernel 2a: per-edge LDS-atomic segment stats ----------------------
__global__ __launch_bounds__(256) void k_stats_partial(
    const float* __restrict__ sv, const int* __restrict__ edge_index,
    const int* __restrict__ batch, float* __restrict__ ws)
{
    __shared__ float bins[768];
    const int tid = threadIdx.x;
    for (int s = tid; s < 768; s += 256) bins[s] = 0.0f;
    __syncthreads();

    const int e = blockIdx.x * 256 + tid;
    const int g = batch[edge_index[e]];
    const float* p = sv + (size_t)e * 40;
    float v[40];
    #pragma unroll
    for (int j = 0; j < 40; ++j) v[j] = p[j];

    float* bg = bins + g * 48;
    #pragma unroll
    for (int chn = 0; chn < 16; ++chn) {
        atomicAdd(&bg[chn],      v[chn]);
        atomicAdd(&bg[16 + chn], v[chn] * v[chn]);
    }
    #pragma unroll
    for (int o = 0; o < 8; ++o) {
        const float a = v[16 + o*3], b = v[16 + o*3 + 1], c = v[16 + o*3 + 2];
        atomicAdd(&bg[32 + o], a*a + b*b + c*c);
    }
    atomicAdd(&bg[40], 1.0f);
    __syncthreads();

    for (int s = tid; s < 768; s += 256) {
        const float x = bins[s];
        if (x != 0.0f) atomicAdd(&ws[s], x);
    }
}

// ---------------- Kernel 4: stats-finalize (folded) + LN + skip + edge projections --
__global__ __launch_bounds__(256) void k_edge_final(
    float* buf, const float* __restrict__ ws,
    const float* __restrict__ edge_attr, const int* __restrict__ edge_index,
    const int* __restrict__ batch,
    const float* __restrict__ ln_w_s, const float* __restrict__ ln_b_s,
    const float* __restrict__ ln_w_v, const float* __restrict__ w_skip,
    const float* __restrict__ w_edge_s, const float* __restrict__ b_edge_s,
    const float* __restrict__ w_edge_v)
{
    __shared__ float sh_mu[16][16];
    __shared__ float sh_is[16], sh_iv[16];
    __shared__ float sh_lws[16], sh_lbs[16], sh_lwv[8];
    __shared__ float sh_skip[16][16], sh_wes[16][16], sh_bes[16], sh_wev[8][8];
    const int tid = threadIdx.x;
    if (tid < 16) {
        const int g = tid;
        float cnt = ws[g*48 + 40]; if (cnt < 1.0f) cnt = 1.0f;
        const float ic = 1.0f / cnt;
        float vs = 0.0f;
        for (int chn = 0; chn < 16; ++chn) {
            const float mu = ws[g*48 + chn] * ic;
            sh_mu[g][chn] = mu;
            vs += ws[g*48 + 16 + chn] * ic - mu * mu;
        }
        if (vs < 0.0f) vs = 0.0f;
        sh_is[g] = 1.0f / sqrtf(vs * (1.0f/16.0f) + 1e-5f);
        float vv = 0.0f;
        for (int o = 0; o < 8; ++o) vv += ws[g*48 + 32 + o];
        vv = vv * ic * (1.0f/3.0f) * (1.0f/8.0f);
        sh_iv[g] = 1.0f / sqrtf(vv + 1e-5f);
    }
    sh_skip[tid >> 4][tid & 15] = w_skip[tid];
    sh_wes[tid >> 4][tid & 15]  = w_edge_s[tid];
    if (tid < 16) {
        sh_lws[tid] = ln_w_s[tid];
        sh_lbs[tid] = ln_b_s[tid];
        sh_bes[tid] = b_edge_s[tid];
    }
    if (tid < 8)  sh_lwv[tid] = ln_w_v[tid];
    if (tid < 64) sh_wev[tid >> 3][tid & 7] = w_edge_v[tid];
    __syncthreads();

    const int e = blockIdx.x * 256 + tid;
    const int g = batch[edge_index[e]];
    const float d = edge_attr[4*e];
    float es0[16];
    #pragma unroll
    for (int b = 0; b < 16; ++b) {
        const float t = d - 0.4f * (float)b;
        es0[b] = expf(-3.125f * t * t);
    }
    float p[40];
    float* pb = buf + (size_t)e * 40;
    #pragma unroll
    for (int j = 0; j < 40; ++j) p[j] = pb[j];

    const float is = sh_is[g];
    float sn[16];
    #pragma unroll
    for (int chn = 0; chn < 16; ++chn)
        sn[chn] = (p[chn] - sh_mu[g][chn]) * is * sh_lws[chn] + sh_lbs[chn];
    #pragma unroll
    for (int b = 0; b < 16; ++b) {
        const float g0 = es0[b];
        #pragma unroll
        for (int chn = 0; chn < 16; ++chn) sn[chn] += g0 * sh_skip[b][chn];
    }
    #pragma unroll
    for (int o = 0; o < 16; ++o) {
        float a = sh_bes[o];
        #pragma unroll
        for (int chn = 0; chn < 16; ++chn) a += sn[chn] * sh_wes[chn][o];
        pb[o] = a;
    }
    const float iv = sh_iv[g];
    float vn[8][3];
    #pragma unroll
    for (int i = 0; i < 8; ++i) {
        const float f = iv * sh_lwv[i];
        vn[i][0] = p[16 + i*3 + 0] * f;
        vn[i][1] = p[16 + i*3 + 1] * f;
        vn[i][2] = p[16 + i*3 + 2] * f;
    }
    #pragma unroll
    for (int o = 0; o < 8; ++o) {
        float r0 = 0.0f, r1 = 0.0f, r2 = 0.0f;
        #pragma unroll
        for (int i = 0; i < 8; ++i) {
            const float w = sh_wev[i][o];
            r0 += vn[i][0] * w; r1 += vn[i][1] * w; r2 += vn[i][2] * w;
        }
        pb[16 + o*3 + 0] = r0;
        pb[16 + o*3 + 1] = r1;
        pb[16 + o*3 + 2] = r2;
    }
}

extern "C" void kernel_launch(void* const* d_in, const int* in_sizes, int n_in,
                              void* d_out, int out_size, void* d_ws, size_t ws_size,
                              hipStream_t stream)
{
    const float* node_fea  = (const float*)d_in[0];
    const float* edge_attr = (const float*)d_in[1];
    const int* edge_index  = (const int*)d_in[2];
    const int* xsp         = (const int*)d_in[3];
    const int* batch       = (const int*)d_in[4];
    const float* w_rh      = (const float*)d_in[5];
    const float* b_rh      = (const float*)d_in[6];
    const float* w_ro      = (const float*)d_in[7];
    const float* b_ro      = (const float*)d_in[8];
    const float* w_pre     = (const float*)d_in[9];
    const float* b_pre     = (const float*)d_in[10];
    const float* w_sc      = (const float*)d_in[11];
    const float* w_post_s  = (const float*)d_in[12];
    const float* b_post_s  = (const float*)d_in[13];
    const float* w_post_v  = (const float*)d_in[14];
    const float* ln_w_s    = (const float*)d_in[15];
    const float* ln_b_s    = (const float*)d_in[16];
    const float* ln_w_v    = (const float*)d_in[17];
    const float* w_skip    = (const float*)d_in[18];
    const float* w_edge_s  = (const float*)d_in[19];
    const float* b_edge_s  = (const float*)d_in[20];
    const float* w_edge_v  = (const float*)d_in[21];

    float* ws   = (float*)d_ws;
    int*   binv = (int*)(ws + 1056);
    float* out  = (float*)d_out;

    k_init<<<1, 1024, 0, stream>>>(ws, binv);
    k_edge_heavy<<<2048, 256, 0, stream>>>(node_fea, edge_attr, edge_index, xsp,
        w_rh, b_rh, w_ro, b_ro, w_pre, b_pre, w_sc, w_post_s, b_post_s, w_post_v,
        binv, out);
    k_stats_partial<<<256, 256, 0, stream>>>(out, edge_index, batch, ws);
    k_edge_final<<<256, 256, 0, stream>>>(out, ws, edge_attr, edge_index,
        batch, ln_w_s, ln_b_s, ln_w_v, w_skip, w_edge_s, b_edge_s, w_edge_v);
}

// Round 15
// 411.086 us; speedup vs baseline: 2.9183x; 1.0504x over previous
//
#include <hip/hip_runtime.h>

typedef unsigned short u16;
typedef unsigned int u32;
typedef __attribute__((ext_vector_type(8))) _Float16 half8;
typedef __attribute__((ext_vector_type(2))) __fp16 fp16x2;
typedef __attribute__((ext_vector_type(4))) float floatx4;

#define E_TOTAL 65536

__device__ __forceinline__ u32 pk16(float x0, float x1) {
    union { fp16x2 h; u32 u; } c;
    c.h = __builtin_amdgcn_cvt_pkrtz(x0, x1);
    return c.u;
}
union Frag8h { u32 u[4]; half8 v; };

// ws layout (floats): [0:768] per-graph stat sums; ints [1056:1088] = binv.

// ---------------- Init: zero stats + probe MFMA k-pairing (fused) ----------------
__global__ __launch_bounds__(1024) void k_init(float* __restrict__ ws, int* __restrict__ binv) {
    const int tid = threadIdx.x;
    for (int i = tid; i < 1056; i += 1024) ws[i] = 0.0f;
    if (tid < 64) {
        const int lane = tid;
        const int q = lane >> 4;
        if (lane < 32) binv[lane] = lane;    // default identity (safety)
        half8 bfr;
        #pragma unroll
        for (int j = 0; j < 8; ++j) bfr[j] = (_Float16)(float)(q*8 + j + 1);
        #pragma unroll
        for (int s = 0; s < 32; ++s) {
            const int qa = s >> 3, ja = s & 7;
            half8 afr;
            #pragma unroll
            for (int j = 0; j < 8; ++j) afr[j] = (_Float16)0.0f;
            if (q == qa) afr[ja] = (_Float16)1.0f;
            floatx4 dc = {0.0f, 0.0f, 0.0f, 0.0f};
            dc = __builtin_amdgcn_mfma_f32_16x16x32_f16(afr, bfr, dc, 0, 0, 0);
            if (lane == 0) {
                const int sB = (int)(dc[0] + 0.5f) - 1;
                if (sB >= 0 && sB < 32) binv[sB] = s;
            }
        }
    }
}

// ---------------- Kernel 1: heavy conv, 32 edges/block, prefetched 128-col chunks ---
// R14 (334us) + register prefetch: chunk ch+1's 32 weight loads are issued AFTER the
// second __syncthreads (so no vmcnt drain between issue and use) and consumed at the
// top of the next iteration -> in flight during the whole consumer phase.
__global__ __launch_bounds__(256) void k_edge_heavy(
    const float* __restrict__ node_fea, const float* __restrict__ edge_attr,
    const int* __restrict__ edge_index, const int* __restrict__ xsp,
    const float* __restrict__ w_rh, const float* __restrict__ b_rh,
    const float* __restrict__ w_ro, const float* __restrict__ b_ro,
    const float* __restrict__ w_pre, const float* __restrict__ b_pre,
    const float* __restrict__ w_sc, const float* __restrict__ w_post_s,
    const float* __restrict__ b_post_s, const float* __restrict__ w_post_v,
    const int* __restrict__ binv,
    float* __restrict__ out)
{
    __shared__ __align__(16) float sh_wt[32][130];   // 16640 B; prologue overlays here
    __shared__ float sh_sin[32][80];
    __shared__ float sh_vl[32][3][32];
    __shared__ float sh_acc[32][56];
    __shared__ float sh_y1[32][4];
    __shared__ int   sh_kmap[32];

    // Overlay (all dead before first sh_wt write; mutually disjoint):
    u16*   a_rbf = (u16*)&sh_wt[0][0];                     // [0,8192) B
    u16*   a_h   = (u16*)((char*)&sh_wt[0][0] + 8192);     // [8192,12288) B
    float* es0f  = (float*)((char*)&sh_wt[0][0] + 12288);  // [12288,14336) B

    const int tid = threadIdx.x;
    const int ed = tid >> 4, l16 = tid & 15;
    const int lane = tid & 63, w = tid >> 6;
    const int quad = lane >> 4, l15 = lane & 15;
    const int e0 = blockIdx.x * 32 + ed;
    const int e1 = e0 + 16;

    if (tid < 32) sh_kmap[tid] = binv[tid];

    const int ni0 = edge_index[e0], nj0 = edge_index[E_TOTAL + e0];
    const int ni1 = edge_index[e1], nj1 = edge_index[E_TOTAL + e1];
    const float4 ea0 = *(const float4*)(edge_attr + 4*e0);
    const float4 ea1 = *(const float4*)(edge_attr + 4*e1);
    const float d0 = ea0.x, d1 = ea1.x;
    {
        const float invn0 = 1.0f / (sqrtf(ea0.y*ea0.y + ea0.z*ea0.z + ea0.w*ea0.w) + 1e-12f);
        const float invn1 = 1.0f / (sqrtf(ea1.y*ea1.y + ea1.z*ea1.z + ea1.w*ea1.w) + 1e-12f);
        if (l16 == 0) {
            sh_y1[ed][0]    = 1.7320508075688772f * ea0.y * invn0;
            sh_y1[ed][1]    = 1.7320508075688772f * ea0.z * invn0;
            sh_y1[ed][2]    = 1.7320508075688772f * ea0.w * invn0;
            sh_y1[16+ed][0] = 1.7320508075688772f * ea1.y * invn1;
            sh_y1[16+ed][1] = 1.7320508075688772f * ea1.z * invn1;
            sh_y1[16+ed][2] = 1.7320508075688772f * ea1.w * invn1;
        }
    }

    // rbf -> fp16 A-fragments for both groups (into overlay)
    const float C128 = -0.5f * (127.0f/6.0f) * (127.0f/6.0f);
    const float S128 = 6.0f/127.0f;
    {
        Frag8h t0, t1;
        #pragma unroll
        for (int r2 = 0; r2 < 4; ++r2) {
            const int b0i = l16*8 + 2*r2;
            const float u0 = d0 - S128 * (float)b0i;
            const float u1 = d0 - S128 * (float)(b0i + 1);
            const float v0 = d1 - S128 * (float)b0i;
            const float v1 = d1 - S128 * (float)(b0i + 1);
            t0.u[r2] = pk16(expf(C128*u0*u0), expf(C128*u1*u1));
            t1.u[r2] = pk16(expf(C128*v0*v0), expf(C128*v1*v1));
        }
        *(half8*)&a_rbf[(l16*16 + ed)*8]        = t0.v;
        *(half8*)&a_rbf[2048 + (l16*16 + ed)*8] = t1.v;
    }
    {
        const float t0 = d0 - 0.4f * (float)l16;
        const float t1 = d1 - 0.4f * (float)l16;
        es0f[ed*16 + l16]      = expf(-3.125f * t0 * t0);
        es0f[(16+ed)*16 + l16] = expf(-3.125f * t1 * t1);
    }

    const float rs80 = 0.11180339887498949f;
    const float rs32 = 0.17677669529663689f;
    {
        const float* fi = node_fea + (size_t)ni0 * 80;
        const float* fj = node_fea + (size_t)nj0 * 80;
        sh_sin[ed][2*l16+0]    = fi[2*l16+0] * rs80;
        sh_sin[ed][2*l16+1]    = fi[2*l16+1] * rs80;
        sh_sin[ed][32+2*l16+0] = fj[2*l16+0] * rs80;
        sh_sin[ed][32+2*l16+1] = fj[2*l16+1] * rs80;
        #pragma unroll
        for (int c = 0; c < 3; ++c) {
            sh_vl[ed][c][l16]      = fi[32 + 3*l16 + c] * rs32;
            sh_vl[ed][c][16 + l16] = fj[32 + 3*l16 + c] * rs32;
        }
    }
    {
        const float* fi = node_fea + (size_t)ni1 * 80;
        const float* fj = node_fea + (size_t)nj1 * 80;
        sh_sin[16+ed][2*l16+0]    = fi[2*l16+0] * rs80;
        sh_sin[16+ed][2*l16+1]    = fi[2*l16+1] * rs80;
        sh_sin[16+ed][32+2*l16+0] = fj[2*l16+0] * rs80;
        sh_sin[16+ed][32+2*l16+1] = fj[2*l16+1] * rs80;
        #pragma unroll
        for (int c = 0; c < 3; ++c) {
            sh_vl[16+ed][c][l16]      = fi[32 + 3*l16 + c] * rs32;
            sh_vl[16+ed][c][16 + l16] = fj[32 + 3*l16 + c] * rs32;
        }
    }
    for (int s = tid; s < 32*56; s += 256) (&sh_acc[0][0])[s] = 0.0f;
    __syncthreads();

    int km[8];
    u32 voff0[8], voff1[8];
    #pragma unroll
    for (int j = 0; j < 8; ++j) {
        km[j] = sh_kmap[quad*8 + j];
        voff0[j] = (u32)(km[j] * 3840 + l15);
        voff1[j] = voff0[j] + 32u * 3840u;
    }

    // edge_s + sc for both edges (reads es0f overlay)
    float my_sc0, my_sc1;
    {
        const int o = l16;
        float es0v = b_pre[o], sc0 = 0.0f;
        float es1v = b_pre[o], sc1 = 0.0f;
        const int p0 = 4*xsp[ni0] + xsp[nj0];
        const int p1 = 4*xsp[ni1] + xsp[nj1];
        #pragma unroll
        for (int i = 0; i < 16; ++i) {
            const float g0 = es0f[ed*16 + i];
            const float g1 = es0f[(16+ed)*16 + i];
            es0v += g0 * w_pre[i*16 + o];
            es1v += g1 * w_pre[i*16 + o];
            sc0  += g0 * w_sc[(i*16 + p0)*16 + o];
            sc1  += g1 * w_sc[(i*16 + p1)*16 + o];
        }
        sh_sin[ed][64 + o]    = es0v * rs80;
        sh_sin[16+ed][64 + o] = es1v * rs80;
        my_sc0 = sc0 * 0.0625f;
        my_sc1 = sc1 * 0.0625f;
    }

    // h = silu(rbf @ w_rh + b_rh), both groups share B  (reads a_rbf, writes a_h)
    {
        floatx4 h0 = {0.0f, 0.0f, 0.0f, 0.0f};
        floatx4 h1 = {0.0f, 0.0f, 0.0f, 0.0f};
        #pragma unroll
        for (int kk = 0; kk < 4; ++kk) {
            const half8 ag0 = *(const half8*)&a_rbf[((kk*4 + quad)*16 + l15)*8];
            const half8 ag1 = *(const half8*)&a_rbf[2048 + ((kk*4 + quad)*16 + l15)*8];
            Frag8h bh;
            #pragma unroll
            for (int jj = 0; jj < 4; ++jj) {
                const float x0 = w_rh[(size_t)(kk*32 + km[2*jj+0])*64 + w*16 + l15];
                const float x1 = w_rh[(size_t)(kk*32 + km[2*jj+1])*64 + w*16 + l15];
                bh.u[jj] = pk16(x0, x1);
            }
            h0 = __builtin_amdgcn_mfma_f32_16x16x32_f16(ag0, bh.v, h0, 0, 0, 0);
            h1 = __builtin_amdgcn_mfma_f32_16x16x32_f16(ag1, bh.v, h1, 0, 0, 0);
        }
        const int hn = w*16 + l15;
        const float bb = b_rh[hn];
        const int k8 = hn >> 3, j2 = hn & 7;
        #pragma unroll
        for (int r = 0; r < 4; ++r) {
            const int m = quad*4 + r;
            {
                const float x = h0[r] + bb;
                const float s = x / (1.0f + expf(-x));
                union { _Float16 h; u16 u; } cv; cv.h = (_Float16)s;
                a_h[(k8*16 + m)*8 + j2] = cv.u;
            }
            {
                const float x = h1[r] + bb;
                const float s = x / (1.0f + expf(-x));
                union { _Float16 h; u16 u; } cv; cv.h = (_Float16)s;
                a_h[1024 + (k8*16 + m)*8 + j2] = cv.u;
            }
        }
    }
    __syncthreads();

    // A-fragments into registers (overlay dies after this point)
    const half8 a0g0 = *(const half8*)&a_h[((0*4 + quad)*16 + l15)*8];
    const half8 a1g0 = *(const half8*)&a_h[((1*4 + quad)*16 + l15)*8];
    const half8 a0g1 = *(const half8*)&a_h[1024 + ((0*4 + quad)*16 + l15)*8];
    const half8 a1g1 = *(const half8*)&a_h[1024 + ((1*4 + quad)*16 + l15)*8];

    // Prefetch buffer: pf[ct*16 + {0..7}]=khalf0, pf[ct*16+8+{0..7}]=khalf1 (static idx)
    float pf[32];
    float pbias[2];
    #pragma unroll
    for (int ct = 0; ct < 2; ++ct) {
        const int sgct = __builtin_amdgcn_readfirstlane(w*2 + ct);   // chunk 0
        const float* bp = w_ro + sgct*16;
        #pragma unroll
        for (int j = 0; j < 8; ++j) {
            pf[ct*16 + j]     = bp[voff0[j]];
            pf[ct*16 + 8 + j] = bp[voff1[j]];
        }
        pbias[ct] = b_ro[sgct*16 + l15];
    }

    // -------- main loop: 30 chunks x 128 cols; loads for ch+1 fly under consumers ----
    for (int ch = 0; ch < 30; ++ch) {
        const int coff = ch * 128;
        floatx4 acc0[2], acc1[2];
        float bias[2];
        #pragma unroll
        for (int ct = 0; ct < 2; ++ct) {
            Frag8h b0, b1;
            #pragma unroll
            for (int jj = 0; jj < 4; ++jj) {
                b0.u[jj] = pk16(pf[ct*16 + 2*jj],     pf[ct*16 + 2*jj+1]);
                b1.u[jj] = pk16(pf[ct*16 + 8 + 2*jj], pf[ct*16 + 8 + 2*jj+1]);
            }
            floatx4 a = {0.0f, 0.0f, 0.0f, 0.0f};
            a = __builtin_amdgcn_mfma_f32_16x16x32_f16(a0g0, b0.v, a, 0, 0, 0);
            a = __builtin_amdgcn_mfma_f32_16x16x32_f16(a1g0, b1.v, a, 0, 0, 0);
            acc0[ct] = a;
            floatx4 c = {0.0f, 0.0f, 0.0f, 0.0f};
            c = __builtin_amdgcn_mfma_f32_16x16x32_f16(a0g1, b0.v, c, 0, 0, 0);
            c = __builtin_amdgcn_mfma_f32_16x16x32_f16(a1g1, b1.v, c, 0, 0, 0);
            acc1[ct] = c;
            bias[ct] = pbias[ct];
        }
        __syncthreads();   // previous chunk's consumers done with sh_wt
        #pragma unroll
        for (int ct = 0; ct < 2; ++ct) {
            const int col = w*32 + ct*16 + l15;
            #pragma unroll
            for (int r = 0; r < 4; ++r) {
                sh_wt[quad*4 + r][col]      = acc0[ct][r] + bias[ct];
                sh_wt[16 + quad*4 + r][col] = acc1[ct][r] + bias[ct];
            }
        }
        __syncthreads();

        // prefetch chunk ch+1 (issued AFTER the drain; in flight during consumers)
        if (ch < 29) {
            #pragma unroll
            for (int ct = 0; ct < 2; ++ct) {
                const int sgct = __builtin_amdgcn_readfirstlane((ch+1)*8 + w*2 + ct);
                const float* bp = w_ro + sgct*16;
                #pragma unroll
                for (int j = 0; j < 8; ++j) {
                    pf[ct*16 + j]     = bp[voff0[j]];
                    pf[ct*16 + 8 + j] = bp[voff1[j]];
                }
                pbias[ct] = b_ro[sgct*16 + l15];
            }
        }

        if (ch < 15) {          // w1: cols 0..1920, 24-wide -> s_conv (dynamic bounds)
            for (int idx = tid; idx < 768; idx += 256) {
                const int eo = idx / 24, o = idx % 24;
                const int i0 = (coff > o) ? (coff - o + 23) / 24 : 0;
                int i1 = (coff + 128 - o + 23) / 24; if (i1 > 80) i1 = 80;
                float a = 0.0f;
                for (int i = i0; i < i1; ++i)
                    a += sh_sin[eo][i] * sh_wt[eo][i*24 + o - coff];
                sh_acc[eo][o] += a;
            }
        } else if (ch < 20) {   // w2: 16 rows x 8 per chunk (STATIC)
            const int ib = (ch - 15) * 16;
            for (int idx = tid; idx < 256; idx += 256) {
                const int eo = idx >> 3, o = idx & 7;
                float a = 0.0f;
                #pragma unroll
                for (int i = 0; i < 16; ++i)
                    a += sh_sin[eo][ib + i] * sh_wt[eo][i*8 + o];
                sh_acc[eo][24 + o] += a;
            }
        } else if (ch < 22) {   // w3: 16 rows x 8 per chunk, left = v_in[:,c] (STATIC)
            const int ib = (ch - 20) * 16;
            for (int idx = tid; idx < 768; idx += 256) {
                const int eo = idx / 24, rem = idx % 24;
                const int o = rem / 3, cc = rem % 3;
                float a = 0.0f;
                #pragma unroll
                for (int i = 0; i < 16; ++i)
                    a += sh_vl[eo][cc][ib + i] * sh_wt[eo][i*8 + o];
                sh_acc[eo][32 + o*3 + cc] += a;
            }
        } else if (ch < 28) {   // w4: cols 2816..3584, 24-wide, q inline (dynamic)
            const int rel = coff - 2816;
            for (int idx = tid; idx < 768; idx += 256) {
                const int eo = idx / 24, o = idx % 24;
                const int i0 = (rel > o) ? (rel - o + 23) / 24 : 0;
                int i1 = (rel + 128 - o + 23) / 24; if (i1 > 32) i1 = 32;
                const float Ya = sh_y1[eo][0], Yb = sh_y1[eo][1], Yc = sh_y1[eo][2];
                float a = 0.0f;
                for (int i = i0; i < i1; ++i) {
                    const float qv = sh_vl[eo][0][i]*Ya + sh_vl[eo][1][i]*Yb
                                   + sh_vl[eo][2][i]*Yc;
                    a += qv * sh_wt[eo][i*24 + o - rel];
                }
                sh_acc[eo][o] += a * 0.57735026918962573f;
            }
        } else {                // w5: 16 rows x 8 per chunk, cross inline (STATIC)
            const int ib = (ch - 28) * 16;
            for (int idx = tid; idx < 768; idx += 256) {
                const int eo = idx / 24, rem = idx % 24;
                const int o = rem / 3, cc = rem % 3;
                const int c1 = (cc < 2) ? cc + 1 : 0;
                const int c2 = (c1 < 2) ? c1 + 1 : 0;
                const float Yp = sh_y1[eo][c2];
                const float Ym = sh_y1[eo][c1];
                float a = 0.0f;
                #pragma unroll
                for (int i = 0; i < 16; ++i)
                    a += (sh_vl[eo][c1][ib+i]*Yp - sh_vl[eo][c2][ib+i]*Ym) * sh_wt[eo][i*8 + o];
                sh_acc[eo][32 + o*3 + cc] += a * 0.70710678118654746f;
            }
        }
    }
    __syncthreads();

    // -------- epilogue: both edges --------
    #pragma unroll
    for (int g = 0; g < 2; ++g) {
        const int er = g*16 + ed;
        const int e  = (g == 0) ? e0 : e1;
        const float msc = (g == 0) ? my_sc0 : my_sc1;
        {
            const int o = l16;
            float a = b_post_s[o] + msc;
            #pragma unroll
            for (int i = 0; i < 16; ++i) {
                const float sv = sh_acc[er][i];
                a += (sv / (1.0f + expf(-sv))) * w_post_s[i*16 + o];
            }
            out[(size_t)e*40 + o] = a;
        }
        if (l16 < 8) {
            const int o = l16;
            const float Ya = sh_y1[er][0], Yb = sh_y1[er][1], Yc = sh_y1[er][2];
            float r0 = 0.0f, r1 = 0.0f, r2 = 0.0f;
            #pragma unroll
            for (int i = 0; i < 8; ++i) {
                const float gt = 1.0f / (1.0f + expf(-sh_acc[er][16 + i]));
                const float a2 = sh_acc[er][24 + i];
                const float ww = w_post_v[i*8 + o];
                r0 += (a2*Ya + sh_acc[er][32 + i*3 + 0]) * gt * ww;
                r1 += (a2*Yb + sh_acc[er][32 + i*3 + 1]) * gt * ww;
                r2 += (a2*Yc + sh_acc[er][32 + i*3 + 2]) * gt * ww;
            }
            out[(size_t)e*40 + 16 + o*3 + 0] = r0;
            out[(size_t)e*40 + 16 + o*3 + 1] = r1;
            out[(size_t)e*40 + 16 + o*3 + 2] = r2;
        }
    }
}

// ---------------- Kernel 2a: per-edge LDS-atomic segment stats ----------------------
__global__ __launch_bounds__(256) void k_stats_partial(
    const float* __restrict__ sv, const int* __restrict__ edge_index,
    const int* __restrict__ batch, float* __restrict__ ws)
{
    __shared__ float bins[768];
    const int tid = threadIdx.x;
    for (int s = tid; s < 768; s += 256) bins[s] = 0.0f;
    __syncthreads();

    const int e = blockIdx.x * 256 + tid;
    const int g = batch[edge_index[e]];
    const float* p = sv + (size_t)e * 40;
    float v[40];
    #pragma unroll
    for (int j = 0; j < 40; ++j) v[j] = p[j];

    float* bg = bins + g * 48;
    #pragma unroll
    for (int chn = 0; chn < 16; ++chn) {
        atomicAdd(&bg[chn],      v[chn]);
        atomicAdd(&bg[16 + chn], v[chn] * v[chn]);
    }
    #pragma unroll
    for (int o = 0; o < 8; ++o) {
        const float a = v[16 + o*3], b = v[16 + o*3 + 1], c = v[16 + o*3 + 2];
        atomicAdd(&bg[32 + o], a*a + b*b + c*c);
    }
    atomicAdd(&bg[40], 1.0f);
    __syncthreads();

    for (int s = tid; s < 768; s += 256) {
        const float x = bins[s];
        if (x != 0.0f) atomicAdd(&ws[s], x);
    }
}

// ---------------- Kernel 4: stats-finalize (folded) + LN + skip + edge projections --
__global__ __launch_bounds__(256) void k_edge_final(
    float* buf, const float* __restrict__ ws,
    const float* __restrict__ edge_attr, const int* __restrict__ edge_index,
    const int* __restrict__ batch,
    const float* __restrict__ ln_w_s, const float* __restrict__ ln_b_s,
    const float* __restrict__ ln_w_v, const float* __restrict__ w_skip,
    const float* __restrict__ w_edge_s, const float* __restrict__ b_edge_s,
    const float* __restrict__ w_edge_v)
{
    __shared__ float sh_mu[16][16];
    __shared__ float sh_is[16], sh_iv[16];
    __shared__ float sh_lws[16], sh_lbs[16], sh_lwv[8];
    __shared__ float sh_skip[16][16], sh_wes[16][16], sh_bes[16], sh_wev[8][8];
    const int tid = threadIdx.x;
    if (tid < 16) {
        const int g = tid;
        float cnt = ws[g*48 + 40]; if (cnt < 1.0f) cnt = 1.0f;
        const float ic = 1.0f / cnt;
        float vs = 0.0f;
        for (int chn = 0; chn < 16; ++chn) {
            const float mu = ws[g*48 + chn] * ic;
            sh_mu[g][chn] = mu;
            vs += ws[g*48 + 16 + chn] * ic - mu * mu;
        }
        if (vs < 0.0f) vs = 0.0f;
        sh_is[g] = 1.0f / sqrtf(vs * (1.0f/16.0f) + 1e-5f);
        float vv = 0.0f;
        for (int o = 0; o < 8; ++o) vv += ws[g*48 + 32 + o];
        vv = vv * ic * (1.0f/3.0f) * (1.0f/8.0f);
        sh_iv[g] = 1.0f / sqrtf(vv + 1e-5f);
    }
    sh_skip[tid >> 4][tid & 15] = w_skip[tid];
    sh_wes[tid >> 4][tid & 15]  = w_edge_s[tid];
    if (tid < 16) {
        sh_lws[tid] = ln_w_s[tid];
        sh_lbs[tid] = ln_b_s[tid];
        sh_bes[tid] = b_edge_s[tid];
    }
    if (tid < 8)  sh_lwv[tid] = ln_w_v[tid];
    if (tid < 64) sh_wev[tid >> 3][tid & 7] = w_edge_v[tid];
    __syncthreads();

    const int e = blockIdx.x * 256 + tid;
    const int g = batch[edge_index[e]];
    const float d = edge_attr[4*e];
    float es0[16];
    #pragma unroll
    for (int b = 0; b < 16; ++b) {
        const float t = d - 0.4f * (float)b;
        es0[b] = expf(-3.125f * t * t);
    }
    float p[40];
    float* pb = buf + (size_t)e * 40;
    #pragma unroll
    for (int j = 0; j < 40; ++j) p[j] = pb[j];

    const float is = sh_is[g];
    float sn[16];
    #pragma unroll
    for (int chn = 0; chn < 16; ++chn)
        sn[chn] = (p[chn] - sh_mu[g][chn]) * is * sh_lws[chn] + sh_lbs[chn];
    #pragma unroll
    for (int b = 0; b < 16; ++b) {
        const float g0 = es0[b];
        #pragma unroll
        for (int chn = 0; chn < 16; ++chn) sn[chn] += g0 * sh_skip[b][chn];
    }
    #pragma unroll
    for (int o = 0; o < 16; ++o) {
        float a = sh_bes[o];
        #pragma unroll
        for (int chn = 0; chn < 16; ++chn) a += sn[chn] * sh_wes[chn][o];
        pb[o] = a;
    }
    const float iv = sh_iv[g];
    float vn[8][3];
    #pragma unroll
    for (int i = 0; i < 8; ++i) {
        const float f = iv * sh_lwv[i];
        vn[i][0] = p[16 + i*3 + 0] * f;
        vn[i][1] = p[16 + i*3 + 1] * f;
        vn[i][2] = p[16 + i*3 + 2] * f;
    }
    #pragma unroll
    for (int o = 0; o < 8; ++o) {
        float r0 = 0.0f, r1 = 0.0f, r2 = 0.0f;
        #pragma unroll
        for (int i = 0; i < 8; ++i) {
            const float w = sh_wev[i][o];
            r0 += vn[i][0] * w; r1 += vn[i][1] * w; r2 += vn[i][2] * w;
        }
        pb[16 + o*3 + 0] = r0;
        pb[16 + o*3 + 1] = r1;
        pb[16 + o*3 + 2] = r2;
    }
}

extern "C" void kernel_launch(void* const* d_in, const int* in_sizes, int n_in,
                              void* d_out, int out_size, void* d_ws, size_t ws_size,
                              hipStream_t stream)
{
    const float* node_fea  = (const float*)d_in[0];
    const float* edge_attr = (const float*)d_in[1];
    const int* edge_index  = (const int*)d_in[2];
    const int* xsp         = (const int*)d_in[3];
    const int* batch       = (const int*)d_in[4];
    const float* w_rh      = (const float*)d_in[5];
    const float* b_rh      = (const float*)d_in[6];
    const float* w_ro      = (const float*)d_in[7];
    const float* b_ro      = (const float*)d_in[8];
    const float* w_pre     = (const float*)d_in[9];
    const float* b_pre     = (const float*)d_in[10];
    const float* w_sc      = (const float*)d_in[11];
    const float* w_post_s  = (const float*)d_in[12];
    const float* b_post_s  = (const float*)d_in[13];
    const float* w_post_v  = (const float*)d_in[14];
    const float* ln_w_s    = (const float*)d_in[15];
    const float* ln_b_s    = (const float*)d_in[16];
    const float* ln_w_v    = (const float*)d_in[17];
    const float* w_skip    = (const float*)d_in[18];
    const float* w_edge_s  = (const float*)d_in[19];
    const float* b_edge_s  = (const float*)d_in[20];
    const float* w_edge_v  = (const float*)d_in[21];

    float* ws   = (float*)d_ws;
    int*   binv = (int*)(ws + 1056);
    float* out  = (float*)d_out;

    k_init<<<1, 1024, 0, stream>>>(ws, binv);
    k_edge_heavy<<<2048, 256, 0, stream>>>(node_fea, edge_attr, edge_index, xsp,
        w_rh, b_rh, w_ro, b_ro, w_pre, b_pre, w_sc, w_post_s, b_post_s, w_post_v,
        binv, out);
    k_stats_partial<<<256, 256, 0, stream>>>(out, edge_index, batch, ws);
    k_edge_final<<<256, 256, 0, stream>>>(out, ws, edge_attr, edge_index,
        batch, ln_w_s, ln_b_s, ln_w_v, w_skip, w_edge_s, b_edge_s, w_edge_v);
}

// Round 16
// 406.895 us; speedup vs baseline: 2.9484x; 1.0103x over previous
//
#include <hip/hip_runtime.h>

typedef unsigned short u16;
typedef unsigned int u32;
typedef __attribute__((ext_vector_type(8))) _Float16 half8;
typedef __attribute__((ext_vector_type(2))) __fp16 fp16x2;
typedef __attribute__((ext_vector_type(4))) float floatx4;

#define E_TOTAL 65536

__device__ __forceinline__ u32 pk16(float x0, float x1) {
    union { fp16x2 h; u32 u; } c;
    c.h = __builtin_amdgcn_cvt_pkrtz(x0, x1);
    return c.u;
}
union Frag8h { u32 u[4]; half8 v; };

// ws layout (floats): [0:768] per-graph stat sums; ints [1056:1088] = binv.

// ---------------- Init: zero stats + probe MFMA k-pairing (fused) ----------------
__global__ __launch_bounds__(1024) void k_init(float* __restrict__ ws, int* __restrict__ binv) {
    const int tid = threadIdx.x;
    for (int i = tid; i < 1056; i += 1024) ws[i] = 0.0f;
    if (tid < 64) {
        const int lane = tid;
        const int q = lane >> 4;
        if (lane < 32) binv[lane] = lane;    // default identity (safety)
        half8 bfr;
        #pragma unroll
        for (int j = 0; j < 8; ++j) bfr[j] = (_Float16)(float)(q*8 + j + 1);
        #pragma unroll
        for (int s = 0; s < 32; ++s) {
            const int qa = s >> 3, ja = s & 7;
            half8 afr;
            #pragma unroll
            for (int j = 0; j < 8; ++j) afr[j] = (_Float16)0.0f;
            if (q == qa) afr[ja] = (_Float16)1.0f;
            floatx4 dc = {0.0f, 0.0f, 0.0f, 0.0f};
            dc = __builtin_amdgcn_mfma_f32_16x16x32_f16(afr, bfr, dc, 0, 0, 0);
            if (lane == 0) {
                const int sB = (int)(dc[0] + 0.5f) - 1;
                if (sB >= 0 && sB < 32) binv[sB] = s;
            }
        }
    }
}

// ---------------- Kernel 1: heavy conv, 32 edges/block, prefetch + dbuf sh_wt -------
// R15 (307us) + (a) double-buffered sh_wt -> ONE barrier per chunk (was 2);
// (b) segment stats folded into the epilogue (k_stats_partial eliminated).
__global__ __launch_bounds__(256) void k_edge_heavy(
    const float* __restrict__ node_fea, const float* __restrict__ edge_attr,
    const int* __restrict__ edge_index, const int* __restrict__ xsp,
    const float* __restrict__ w_rh, const float* __restrict__ b_rh,
    const float* __restrict__ w_ro, const float* __restrict__ b_ro,
    const float* __restrict__ w_pre, const float* __restrict__ b_pre,
    const float* __restrict__ w_sc, const float* __restrict__ w_post_s,
    const float* __restrict__ b_post_s, const float* __restrict__ w_post_v,
    const int* __restrict__ binv, const int* __restrict__ batch,
    float* __restrict__ ws_stats,
    float* __restrict__ out)
{
    __shared__ __align__(16) float sh_wt[2][32][130];   // 33280 B; overlays below
    __shared__ float sh_sin[32][80];
    __shared__ float sh_vl[32][3][32];
    __shared__ float sh_acc[32][56];
    __shared__ float sh_y1[32][4];
    __shared__ int   sh_kmap[32];

    // Prologue overlay (dead before first sh_wt write; fenced by extra barrier):
    u16*   a_rbf = (u16*)&sh_wt[0][0][0];                     // [0,8192) B
    u16*   a_h   = (u16*)((char*)&sh_wt[0][0][0] + 8192);     // [8192,12288) B
    float* es0f  = (float*)((char*)&sh_wt[0][0][0] + 12288);  // [12288,14336) B

    const int tid = threadIdx.x;
    const int ed = tid >> 4, l16 = tid & 15;
    const int lane = tid & 63, w = tid >> 6;
    const int quad = lane >> 4, l15 = lane & 15;
    const int e0 = blockIdx.x * 32 + ed;
    const int e1 = e0 + 16;

    if (tid < 32) sh_kmap[tid] = binv[tid];

    const int ni0 = edge_index[e0], nj0 = edge_index[E_TOTAL + e0];
    const int ni1 = edge_index[e1], nj1 = edge_index[E_TOTAL + e1];
    const float4 ea0 = *(const float4*)(edge_attr + 4*e0);
    const float4 ea1 = *(const float4*)(edge_attr + 4*e1);
    const float d0 = ea0.x, d1 = ea1.x;
    {
        const float invn0 = 1.0f / (sqrtf(ea0.y*ea0.y + ea0.z*ea0.z + ea0.w*ea0.w) + 1e-12f);
        const float invn1 = 1.0f / (sqrtf(ea1.y*ea1.y + ea1.z*ea1.z + ea1.w*ea1.w) + 1e-12f);
        if (l16 == 0) {
            sh_y1[ed][0]    = 1.7320508075688772f * ea0.y * invn0;
            sh_y1[ed][1]    = 1.7320508075688772f * ea0.z * invn0;
            sh_y1[ed][2]    = 1.7320508075688772f * ea0.w * invn0;
            sh_y1[16+ed][0] = 1.7320508075688772f * ea1.y * invn1;
            sh_y1[16+ed][1] = 1.7320508075688772f * ea1.z * invn1;
            sh_y1[16+ed][2] = 1.7320508075688772f * ea1.w * invn1;
        }
    }

    // rbf -> fp16 A-fragments for both groups (into overlay)
    const float C128 = -0.5f * (127.0f/6.0f) * (127.0f/6.0f);
    const float S128 = 6.0f/127.0f;
    {
        Frag8h t0, t1;
        #pragma unroll
        for (int r2 = 0; r2 < 4; ++r2) {
            const int b0i = l16*8 + 2*r2;
            const float u0 = d0 - S128 * (float)b0i;
            const float u1 = d0 - S128 * (float)(b0i + 1);
            const float v0 = d1 - S128 * (float)b0i;
            const float v1 = d1 - S128 * (float)(b0i + 1);
            t0.u[r2] = pk16(expf(C128*u0*u0), expf(C128*u1*u1));
            t1.u[r2] = pk16(expf(C128*v0*v0), expf(C128*v1*v1));
        }
        *(half8*)&a_rbf[(l16*16 + ed)*8]        = t0.v;
        *(half8*)&a_rbf[2048 + (l16*16 + ed)*8] = t1.v;
    }
    {
        const float t0 = d0 - 0.4f * (float)l16;
        const float t1 = d1 - 0.4f * (float)l16;
        es0f[ed*16 + l16]      = expf(-3.125f * t0 * t0);
        es0f[(16+ed)*16 + l16] = expf(-3.125f * t1 * t1);
    }

    const float rs80 = 0.11180339887498949f;
    const float rs32 = 0.17677669529663689f;
    {
        const float* fi = node_fea + (size_t)ni0 * 80;
        const float* fj = node_fea + (size_t)nj0 * 80;
        sh_sin[ed][2*l16+0]    = fi[2*l16+0] * rs80;
        sh_sin[ed][2*l16+1]    = fi[2*l16+1] * rs80;
        sh_sin[ed][32+2*l16+0] = fj[2*l16+0] * rs80;
        sh_sin[ed][32+2*l16+1] = fj[2*l16+1] * rs80;
        #pragma unroll
        for (int c = 0; c < 3; ++c) {
            sh_vl[ed][c][l16]      = fi[32 + 3*l16 + c] * rs32;
            sh_vl[ed][c][16 + l16] = fj[32 + 3*l16 + c] * rs32;
        }
    }
    {
        const float* fi = node_fea + (size_t)ni1 * 80;
        const float* fj = node_fea + (size_t)nj1 * 80;
        sh_sin[16+ed][2*l16+0]    = fi[2*l16+0] * rs80;
        sh_sin[16+ed][2*l16+1]    = fi[2*l16+1] * rs80;
        sh_sin[16+ed][32+2*l16+0] = fj[2*l16+0] * rs80;
        sh_sin[16+ed][32+2*l16+1] = fj[2*l16+1] * rs80;
        #pragma unroll
        for (int c = 0; c < 3; ++c) {
            sh_vl[16+ed][c][l16]      = fi[32 + 3*l16 + c] * rs32;
            sh_vl[16+ed][c][16 + l16] = fj[32 + 3*l16 + c] * rs32;
        }
    }
    for (int s = tid; s < 32*56; s += 256) (&sh_acc[0][0])[s] = 0.0f;
    __syncthreads();

    int km[8];
    u32 voff0[8], voff1[8];
    #pragma unroll
    for (int j = 0; j < 8; ++j) {
        km[j] = sh_kmap[quad*8 + j];
        voff0[j] = (u32)(km[j] * 3840 + l15);
        voff1[j] = voff0[j] + 32u * 3840u;
    }

    // edge_s + sc for both edges (reads es0f overlay)
    float my_sc0, my_sc1;
    {
        const int o = l16;
        float es0v = b_pre[o], sc0 = 0.0f;
        float es1v = b_pre[o], sc1 = 0.0f;
        const int p0 = 4*xsp[ni0] + xsp[nj0];
        const int p1 = 4*xsp[ni1] + xsp[nj1];
        #pragma unroll
        for (int i = 0; i < 16; ++i) {
            const float g0 = es0f[ed*16 + i];
            const float g1 = es0f[(16+ed)*16 + i];
            es0v += g0 * w_pre[i*16 + o];
            es1v += g1 * w_pre[i*16 + o];
            sc0  += g0 * w_sc[(i*16 + p0)*16 + o];
            sc1  += g1 * w_sc[(i*16 + p1)*16 + o];
        }
        sh_sin[ed][64 + o]    = es0v * rs80;
        sh_sin[16+ed][64 + o] = es1v * rs80;
        my_sc0 = sc0 * 0.0625f;
        my_sc1 = sc1 * 0.0625f;
    }

    // h = silu(rbf @ w_rh + b_rh), both groups share B  (reads a_rbf, writes a_h)
    {
        floatx4 h0 = {0.0f, 0.0f, 0.0f, 0.0f};
        floatx4 h1 = {0.0f, 0.0f, 0.0f, 0.0f};
        #pragma unroll
        for (int kk = 0; kk < 4; ++kk) {
            const half8 ag0 = *(const half8*)&a_rbf[((kk*4 + quad)*16 + l15)*8];
            const half8 ag1 = *(const half8*)&a_rbf[2048 + ((kk*4 + quad)*16 + l15)*8];
            Frag8h bh;
            #pragma unroll
            for (int jj = 0; jj < 4; ++jj) {
                const float x0 = w_rh[(size_t)(kk*32 + km[2*jj+0])*64 + w*16 + l15];
                const float x1 = w_rh[(size_t)(kk*32 + km[2*jj+1])*64 + w*16 + l15];
                bh.u[jj] = pk16(x0, x1);
            }
            h0 = __builtin_amdgcn_mfma_f32_16x16x32_f16(ag0, bh.v, h0, 0, 0, 0);
            h1 = __builtin_amdgcn_mfma_f32_16x16x32_f16(ag1, bh.v, h1, 0, 0, 0);
        }
        const int hn = w*16 + l15;
        const float bb = b_rh[hn];
        const int k8 = hn >> 3, j2 = hn & 7;
        #pragma unroll
        for (int r = 0; r < 4; ++r) {
            const int m = quad*4 + r;
            {
                const float x = h0[r] + bb;
                const float s = x / (1.0f + expf(-x));
                union { _Float16 h; u16 u; } cv; cv.h = (_Float16)s;
                a_h[(k8*16 + m)*8 + j2] = cv.u;
            }
            {
                const float x = h1[r] + bb;
                const float s = x / (1.0f + expf(-x));
                union { _Float16 h; u16 u; } cv; cv.h = (_Float16)s;
                a_h[1024 + (k8*16 + m)*8 + j2] = cv.u;
            }
        }
    }
    __syncthreads();

    // A-fragments into registers
    const half8 a0g0 = *(const half8*)&a_h[((0*4 + quad)*16 + l15)*8];
    const half8 a1g0 = *(const half8*)&a_h[((1*4 + quad)*16 + l15)*8];
    const half8 a0g1 = *(const half8*)&a_h[1024 + ((0*4 + quad)*16 + l15)*8];
    const half8 a1g1 = *(const half8*)&a_h[1024 + ((1*4 + quad)*16 + l15)*8];
    __syncthreads();   // overlay fully dead before iter-0's sh_wt[0] write (dbuf fence)

    // Prefetch buffer for chunk 0 (static indexing)
    float pf[32];
    float pbias[2];
    #pragma unroll
    for (int ct = 0; ct < 2; ++ct) {
        const int sgct = __builtin_amdgcn_readfirstlane(w*2 + ct);
        const float* bp = w_ro + sgct*16;
        #pragma unroll
        for (int j = 0; j < 8; ++j) {
            pf[ct*16 + j]     = bp[voff0[j]];
            pf[ct*16 + 8 + j] = bp[voff1[j]];
        }
        pbias[ct] = b_ro[sgct*16 + l15];
    }

    // -------- main loop: 30 chunks x 128 cols; dbuf sh_wt, ONE barrier per chunk ----
    for (int ch = 0; ch < 30; ++ch) {
        const int coff = ch * 128;
        float (*wt)[130] = sh_wt[ch & 1];
        floatx4 acc0[2], acc1[2];
        float bias[2];
        #pragma unroll
        for (int ct = 0; ct < 2; ++ct) {
            Frag8h b0, b1;
            #pragma unroll
            for (int jj = 0; jj < 4; ++jj) {
                b0.u[jj] = pk16(pf[ct*16 + 2*jj],     pf[ct*16 + 2*jj+1]);
                b1.u[jj] = pk16(pf[ct*16 + 8 + 2*jj], pf[ct*16 + 8 + 2*jj+1]);
            }
            floatx4 a = {0.0f, 0.0f, 0.0f, 0.0f};
            a = __builtin_amdgcn_mfma_f32_16x16x32_f16(a0g0, b0.v, a, 0, 0, 0);
            a = __builtin_amdgcn_mfma_f32_16x16x32_f16(a1g0, b1.v, a, 0, 0, 0);
            acc0[ct] = a;
            floatx4 c = {0.0f, 0.0f, 0.0f, 0.0f};
            c = __builtin_amdgcn_mfma_f32_16x16x32_f16(a0g1, b0.v, c, 0, 0, 0);
            c = __builtin_amdgcn_mfma_f32_16x16x32_f16(a1g1, b1.v, c, 0, 0, 0);
            acc1[ct] = c;
            bias[ct] = pbias[ct];
        }
        #pragma unroll
        for (int ct = 0; ct < 2; ++ct) {
            const int col = w*32 + ct*16 + l15;
            #pragma unroll
            for (int r = 0; r < 4; ++r) {
                wt[quad*4 + r][col]      = acc0[ct][r] + bias[ct];
                wt[16 + quad*4 + r][col] = acc1[ct][r] + bias[ct];
            }
        }
        __syncthreads();   // the only barrier: write(p) done -> consumers(p) may read

        // prefetch chunk ch+1 (in flight during consumers)
        if (ch < 29) {
            #pragma unroll
            for (int ct = 0; ct < 2; ++ct) {
                const int sgct = __builtin_amdgcn_readfirstlane((ch+1)*8 + w*2 + ct);
                const float* bp = w_ro + sgct*16;
                #pragma unroll
                for (int j = 0; j < 8; ++j) {
                    pf[ct*16 + j]     = bp[voff0[j]];
                    pf[ct*16 + 8 + j] = bp[voff1[j]];
                }
                pbias[ct] = b_ro[sgct*16 + l15];
            }
        }

        if (ch < 15) {          // w1: cols 0..1920, 24-wide -> s_conv (dynamic bounds)
            for (int idx = tid; idx < 768; idx += 256) {
                const int eo = idx / 24, o = idx % 24;
                const int i0 = (coff > o) ? (coff - o + 23) / 24 : 0;
                int i1 = (coff + 128 - o + 23) / 24; if (i1 > 80) i1 = 80;
                float a = 0.0f;
                for (int i = i0; i < i1; ++i)
                    a += sh_sin[eo][i] * wt[eo][i*24 + o - coff];
                sh_acc[eo][o] += a;
            }
        } else if (ch < 20) {   // w2: 16 rows x 8 per chunk (STATIC)
            const int ib = (ch - 15) * 16;
            for (int idx = tid; idx < 256; idx += 256) {
                const int eo = idx >> 3, o = idx & 7;
                float a = 0.0f;
                #pragma unroll
                for (int i = 0; i < 16; ++i)
                    a += sh_sin[eo][ib + i] * wt[eo][i*8 + o];
                sh_acc[eo][24 + o] += a;
            }
        } else if (ch < 22) {   // w3: 16 rows x 8 per chunk, left = v_in[:,c] (STATIC)
            const int ib = (ch - 20) * 16;
            for (int idx = tid; idx < 768; idx += 256) {
                const int eo = idx / 24, rem = idx % 24;
                const int o = rem / 3, cc = rem % 3;
                float a = 0.0f;
                #pragma unroll
                for (int i = 0; i < 16; ++i)
                    a += sh_vl[eo][cc][ib + i] * wt[eo][i*8 + o];
                sh_acc[eo][32 + o*3 + cc] += a;
            }
        } else if (ch < 28) {   // w4: cols 2816..3584, 24-wide, q inline (dynamic)
            const int rel = coff - 2816;
            for (int idx = tid; idx < 768; idx += 256) {
                const int eo = idx / 24, o = idx % 24;
                const int i0 = (rel > o) ? (rel - o + 23) / 24 : 0;
                int i1 = (rel + 128 - o + 23) / 24; if (i1 > 32) i1 = 32;
                const float Ya = sh_y1[eo][0], Yb = sh_y1[eo][1], Yc = sh_y1[eo][2];
                float a = 0.0f;
                for (int i = i0; i < i1; ++i) {
                    const float qv = sh_vl[eo][0][i]*Ya + sh_vl[eo][1][i]*Yb
                                   + sh_vl[eo][2][i]*Yc;
                    a += qv * wt[eo][i*24 + o - rel];
                }
                sh_acc[eo][o] += a * 0.57735026918962573f;
            }
        } else {                // w5: 16 rows x 8 per chunk, cross inline (STATIC)
            const int ib = (ch - 28) * 16;
            for (int idx = tid; idx < 768; idx += 256) {
                const int eo = idx / 24, rem = idx % 24;
                const int o = rem / 3, cc = rem % 3;
                const int c1 = (cc < 2) ? cc + 1 : 0;
                const int c2 = (c1 < 2) ? c1 + 1 : 0;
                const float Yp = sh_y1[eo][c2];
                const float Ym = sh_y1[eo][c1];
                float a = 0.0f;
                #pragma unroll
                for (int i = 0; i < 16; ++i)
                    a += (sh_vl[eo][c1][ib+i]*Yp - sh_vl[eo][c2][ib+i]*Ym) * wt[eo][i*8 + o];
                sh_acc[eo][32 + o*3 + cc] += a * 0.70710678118654746f;
            }
        }
    }
    __syncthreads();

    // -------- epilogue: outputs + folded segment stats (bins overlay on sh_wt) ------
    float* bins = &sh_wt[0][0][0];   // 768 floats; sh_wt dead after final barrier
    for (int s = tid; s < 768; s += 256) bins[s] = 0.0f;
    __syncthreads();

    const int gi0 = batch[ni0];
    const int gi1 = batch[ni1];
    #pragma unroll
    for (int g = 0; g < 2; ++g) {
        const int er = g*16 + ed;
        const int e  = (g == 0) ? e0 : e1;
        const int gi = (g == 0) ? gi0 : gi1;
        const float msc = (g == 0) ? my_sc0 : my_sc1;
        {
            const int o = l16;
            float a = b_post_s[o] + msc;
            #pragma unroll
            for (int i = 0; i < 16; ++i) {
                const float sv = sh_acc[er][i];
                a += (sv / (1.0f + expf(-sv))) * w_post_s[i*16 + o];
            }
            out[(size_t)e*40 + o] = a;
            atomicAdd(&bins[gi*48 + o], a);
            atomicAdd(&bins[gi*48 + 16 + o], a*a);
            if (o == 0) atomicAdd(&bins[gi*48 + 40], 1.0f);
        }
        if (l16 < 8) {
            const int o = l16;
            const float Ya = sh_y1[er][0], Yb = sh_y1[er][1], Yc = sh_y1[er][2];
            float r0 = 0.0f, r1 = 0.0f, r2 = 0.0f;
            #pragma unroll
            for (int i = 0; i < 8; ++i) {
                const float gt = 1.0f / (1.0f + expf(-sh_acc[er][16 + i]));
                const float a2 = sh_acc[er][24 + i];
                const float ww = w_post_v[i*8 + o];
                r0 += (a2*Ya + sh_acc[er][32 + i*3 + 0]) * gt * ww;
                r1 += (a2*Yb + sh_acc[er][32 + i*3 + 1]) * gt * ww;
                r2 += (a2*Yc + sh_acc[er][32 + i*3 + 2]) * gt * ww;
            }
            out[(size_t)e*40 + 16 + o*3 + 0] = r0;
            out[(size_t)e*40 + 16 + o*3 + 1] = r1;
            out[(size_t)e*40 + 16 + o*3 + 2] = r2;
            atomicAdd(&bins[gi*48 + 32 + o], r0*r0 + r1*r1 + r2*r2);
        }
    }
    __syncthreads();
    for (int s = tid; s < 768; s += 256) {
        const float x = bins[s];
        if (x != 0.0f) atomicAdd(&ws_stats[s], x);
    }
}

// ---------------- Kernel 4: stats-finalize (folded) + LN + skip + edge projections --
__global__ __launch_bounds__(256) void k_edge_final(
    float* buf, const float* __restrict__ ws,
    const float* __restrict__ edge_attr, const int* __restrict__ edge_index,
    const int* __restrict__ batch,
    const float* __restrict__ ln_w_s, const float* __restrict__ ln_b_s,
    const float* __restrict__ ln_w_v, const float* __restrict__ w_skip,
    const float* __restrict__ w_edge_s, const float* __restrict__ b_edge_s,
    const float* __restrict__ w_edge_v)
{
    __shared__ float sh_mu[16][16];
    __shared__ float sh_is[16], sh_iv[16];
    __shared__ float sh_lws[16], sh_lbs[16], sh_lwv[8];
    __shared__ float sh_skip[16][16], sh_wes[16][16], sh_bes[16], sh_wev[8][8];
    const int tid = threadIdx.x;
    if (tid < 16) {
        const int g = tid;
        float cnt = ws[g*48 + 40]; if (cnt < 1.0f) cnt = 1.0f;
        const float ic = 1.0f / cnt;
        float vs = 0.0f;
        for (int chn = 0; chn < 16; ++chn) {
            const float mu = ws[g*48 + chn] * ic;
            sh_mu[g][chn] = mu;
            vs += ws[g*48 + 16 + chn] * ic - mu * mu;
        }
        if (vs < 0.0f) vs = 0.0f;
        sh_is[g] = 1.0f / sqrtf(vs * (1.0f/16.0f) + 1e-5f);
        float vv = 0.0f;
        for (int o = 0; o < 8; ++o) vv += ws[g*48 + 32 + o];
        vv = vv * ic * (1.0f/3.0f) * (1.0f/8.0f);
        sh_iv[g] = 1.0f / sqrtf(vv + 1e-5f);
    }
    sh_skip[tid >> 4][tid & 15] = w_skip[tid];
    sh_wes[tid >> 4][tid & 15]  = w_edge_s[tid];
    if (tid < 16) {
        sh_lws[tid] = ln_w_s[tid];
        sh_lbs[tid] = ln_b_s[tid];
        sh_bes[tid] = b_edge_s[tid];
    }
    if (tid < 8)  sh_lwv[tid] = ln_w_v[tid];
    if (tid < 64) sh_wev[tid >> 3][tid & 7] = w_edge_v[tid];
    __syncthreads();

    const int e = blockIdx.x * 256 + tid;
    const int g = batch[edge_index[e]];
    const float d = edge_attr[4*e];
    float es0[16];
    #pragma unroll
    for (int b = 0; b < 16; ++b) {
        const float t = d - 0.4f * (float)b;
        es0[b] = expf(-3.125f * t * t);
    }
    float p[40];
    float* pb = buf + (size_t)e * 40;
    #pragma unroll
    for (int j = 0; j < 40; ++j) p[j] = pb[j];

    const float is = sh_is[g];
    float sn[16];
    #pragma unroll
    for (int chn = 0; chn < 16; ++chn)
        sn[chn] = (p[chn] - sh_mu[g][chn]) * is * sh_lws[chn] + sh_lbs[chn];
    #pragma unroll
    for (int b = 0; b < 16; ++b) {
        const float g0 = es0[b];
        #pragma unroll
        for (int chn = 0; chn < 16; ++chn) sn[chn] += g0 * sh_skip[b][chn];
    }
    #pragma unroll
    for (int o = 0; o < 16; ++o) {
        float a = sh_bes[o];
        #pragma unroll
        for (int chn = 0; chn < 16; ++chn) a += sn[chn] * sh_wes[chn][o];
        pb[o] = a;
    }
    const float iv = sh_iv[g];
    float vn[8][3];
    #pragma unroll
    for (int i = 0; i < 8; ++i) {
        const float f = iv * sh_lwv[i];
        vn[i][0] = p[16 + i*3 + 0] * f;
        vn[i][1] = p[16 + i*3 + 1] * f;
        vn[i][2] = p[16 + i*3 + 2] * f;
    }
    #pragma unroll
    for (int o = 0; o < 8; ++o) {
        float r0 = 0.0f, r1 = 0.0f, r2 = 0.0f;
        #pragma unroll
        for (int i = 0; i < 8; ++i) {
            const float w = sh_wev[i][o];
            r0 += vn[i][0] * w; r1 += vn[i][1] * w; r2 += vn[i][2] * w;
        }
        pb[16 + o*3 + 0] = r0;
        pb[16 + o*3 + 1] = r1;
        pb[16 + o*3 + 2] = r2;
    }
}

extern "C" void kernel_launch(void* const* d_in, const int* in_sizes, int n_in,
                              void* d_out, int out_size, void* d_ws, size_t ws_size,
                              hipStream_t stream)
{
    const float* node_fea  = (const float*)d_in[0];
    const float* edge_attr = (const float*)d_in[1];
    const int* edge_index  = (const int*)d_in[2];
    const int* xsp         = (const int*)d_in[3];
    const int* batch       = (const int*)d_in[4];
    const float* w_rh      = (const float*)d_in[5];
    const float* b_rh      = (const float*)d_in[6];
    const float* w_ro      = (const float*)d_in[7];
    const float* b_ro      = (const float*)d_in[8];
    const float* w_pre     = (const float*)d_in[9];
    const float* b_pre     = (const float*)d_in[10];
    const float* w_sc      = (const float*)d_in[11];
    const float* w_post_s  = (const float*)d_in[12];
    const float* b_post_s  = (const float*)d_in[13];
    const float* w_post_v  = (const float*)d_in[14];
    const float* ln_w_s    = (const float*)d_in[15];
    const float* ln_b_s    = (const float*)d_in[16];
    const float* ln_w_v    = (const float*)d_in[17];
    const float* w_skip    = (const float*)d_in[18];
    const float* w_edge_s  = (const float*)d_in[19];
    const float* b_edge_s  = (const float*)d_in[20];
    const float* w_edge_v  = (const float*)d_in[21];

    float* ws   = (float*)d_ws;
    int*   binv = (int*)(ws + 1056);
    float* out  = (float*)d_out;

    k_init<<<1, 1024, 0, stream>>>(ws, binv);
    k_edge_heavy<<<2048, 256, 0, stream>>>(node_fea, edge_attr, edge_index, xsp,
        w_rh, b_rh, w_ro, b_ro, w_pre, b_pre, w_sc, w_post_s, b_post_s, w_post_v,
        binv, batch, ws, out);
    k_edge_final<<<256, 256, 0, stream>>>(out, ws, edge_attr, edge_index,
        batch, ln_w_s, ln_b_s, ln_w_v, w_skip, w_edge_s, b_edge_s, w_edge_v);
}